// Round 7
// baseline (605.111 us; speedup 1.0000x reference)
//
#include <hip/hip_runtime.h>
#include <hip/hip_bf16.h>

constexpr int B  = 16;
constexpr int C  = 128;
constexpr int H  = 128;
constexpr int W  = 128;
constexpr int CO = 256;
constexpr int HO = 64;
constexpr int WO = 64;

#define EPSV   1e-8f
#define SLOPE  0.2f

typedef short bf16x8 __attribute__((ext_vector_type(8)));
typedef float f32x4  __attribute__((ext_vector_type(4)));

__device__ __forceinline__ short f2bs(float v) {
    __hip_bfloat16 h = __float2bfloat16(v);
    return *(short*)&h;
}
__device__ __forceinline__ float bs2f(short s) {
    __hip_bfloat16 h = *(__hip_bfloat16*)&s;
    return __bfloat162float(h);
}

// async global->LDS, 16B per lane: LDS dest = uniform base + lane*16 (m104).
__device__ __forceinline__ void gl_lds16(const short* g, short* l) {
    __builtin_amdgcn_global_load_lds(
        (const __attribute__((address_space(1))) void*)g,
        (__attribute__((address_space(3))) void*)l, 16, 0, 0);
}

// ---------------------------------------------------------------------------
// demod: d[conv][b][o] = rsqrt(sum_{i,k}(w[o,i,k]*(s[b,i]+1))^2 + eps)
// ---------------------------------------------------------------------------
__global__ __launch_bounds__(128) void demod_kernel(
    const float* __restrict__ w1, const float* __restrict__ w2,
    const float* __restrict__ s1, const float* __restrict__ s2,
    float* __restrict__ d)
{
    int bid  = blockIdx.x;          // conv*2048 + b*128 + o
    int conv = bid >> 11;
    int b    = (bid >> 7) & 15;
    int o    = bid & 127;
    const float* w = conv ? w2 : w1;
    const float* s = conv ? s2 : s1;
    int i = threadIdx.x;
    float sv = s[b * C + i] + 1.0f;
    const float* wp = w + (o * C + i) * 9;
    float sum = 0.f;
    #pragma unroll
    for (int k = 0; k < 9; ++k) { float t = wp[k] * sv; sum += t * t; }
    #pragma unroll
    for (int off = 32; off; off >>= 1) sum += __shfl_down(sum, off);
    __shared__ float red[2];
    if ((threadIdx.x & 63) == 0) red[threadIdx.x >> 6] = sum;
    __syncthreads();
    if (threadIdx.x == 0) d[bid] = rsqrtf(red[0] + red[1] + EPSV);
}

// ---------------------------------------------------------------------------
// expand -> wave-coalesced B-fragment tiling:
// wm[cb][tap][ocT=oc>>4][icC=ic>>5][(oc&15)*32 + (ic&31)]   (bf16)
// ---------------------------------------------------------------------------
__global__ __launch_bounds__(256) void expand_kernel(
    const float* __restrict__ w1, const float* __restrict__ w2,
    const float* __restrict__ s1, const float* __restrict__ s2,
    const float* __restrict__ d, short* __restrict__ wm)
{
    int idx = blockIdx.x * 256 + threadIdx.x;
    int ic  = idx & 127;
    int oc  = (idx >> 7) & 127;
    int t   = idx >> 14;            // cb*9+tap, < 288
    int tap = t % 9;
    int cb  = t / 9;                // conv*16+b
    int b   = cb & 15;
    int conv= cb >> 4;
    const float* w = conv ? w2 : w1;
    const float* s = conv ? s2 : s1;
    float v = w[(oc * C + ic) * 9 + tap] * (s[b * C + ic] + 1.0f)
            * d[(conv * B + b) * C + oc];
    int dst = cb * 147456
            + ((tap * 8 + (oc >> 4)) * 4 + (ic >> 5)) * 512
            + (oc & 15) * 32 + (ic & 31);
    wm[dst] = f2bs(v);
}

// ---------------------------------------------------------------------------
// dwexpand: dwm[tap][ocT=oc>>4 (16)][icC=ic>>5 (4)][(oc&15)*32+(ic&31)]
// ---------------------------------------------------------------------------
__global__ __launch_bounds__(256) void dwexpand_kernel(
    const float* __restrict__ dw, short* __restrict__ dwm)
{
    int idx = blockIdx.x * 256 + threadIdx.x;   // 16*256*128 = 524288
    int ic  = idx & 127;
    int oc  = (idx >> 7) & 255;
    int tap = idx >> 15;
    int dst = ((tap * 16 + (oc >> 4)) * 4 + (ic >> 5)) * 512
            + (oc & 15) * 32 + (ic & 31);
    dwm[dst] = f2bs(dw[(oc * C + ic) * 16 + tap]);
}

// ---------------------------------------------------------------------------
// nchw(f32) -> nhwc(bf16) transpose of features.
// ---------------------------------------------------------------------------
__global__ __launch_bounds__(256) void nchw2nhwc_kernel(
    const float* __restrict__ in, short* __restrict__ out)
{
    __shared__ short s[128 * 136];
    int bid = blockIdx.x;                   // b*128 + h
    int h = bid & 127, b = bid >> 7;
    int tid = threadIdx.x;
    for (int i = tid; i < 128 * 32; i += 256) {
        int w4 = i & 31, ic = i >> 5;
        float4 v = *(const float4*)&in[((b * C + ic) * H + h) * W + w4 * 4];
        s[(w4 * 4 + 0) * 136 + ic] = f2bs(v.x);
        s[(w4 * 4 + 1) * 136 + ic] = f2bs(v.y);
        s[(w4 * 4 + 2) * 136 + ic] = f2bs(v.z);
        s[(w4 * 4 + 3) * 136 + ic] = f2bs(v.w);
    }
    __syncthreads();
    for (int i = tid; i < 128 * 16; i += 256) {
        int icg = i & 15, w = i >> 4;
        *(uint4*)&out[((b * H + h) * W + w) * C + icg * 8] =
            *(uint4*)&s[w * 136 + icg * 8];
    }
}

// ---------------------------------------------------------------------------
// conv3x3 MFMA implicit GEMM — round-7: m97-style weight pipeline.
// EVIDENCE (r4-r6): both MFMA kernels pin at ~1200cy per SIMD per wave-step
// (16 MFMA = 77cy) regardless of prefetch depth (r5 null) or cache locality
// (r6: FETCH -30%, time flat). Common denominator = per-wave global loads in
// the K loop. m93->m97 ladder: converting reg-staged global operands to
// global_load_lds paced LDS pipeline = +69% on the identical step shape.
// DESIGN:
//  - weights: per step (c,tap) stage 8KB (8 frags x 1KB) into wLds dbuf via
//    global_load_lds w16 (2 issues/wave); one barrier/step; bf = ds_read_b128.
//  - LDS swizzle o^=((o>>7)&3)<<4 (involution) on glload SOURCE + ds_read
//    addr (rule 21: linear dest) -> conflict-free bf reads.
//  - input halved to 64-ic (sIn 180x72 = 25.9KB) to keep 3 blocks/CU
//    (m132: 2 blocks/CU cost 42%). Loop c-outer/tap-inner; ic-half 2 staged
//    in 6 batches at steps 9-11 (ic64-95 -> cols 0-31) and 18-20 (ic96-127
//    -> cols 32-63); writes land >=6 barriers before first read, columns
//    disjoint from concurrent readers.
//  - LDS total 42.3KB; regs ~af32+bf32+acc64+temps < 168 -> (256,3).
//  TRIPWIRES: WRITE_SIZE >> 87MB = spill; dur ~144 = hypothesis falsified.
// ---------------------------------------------------------------------------
__global__ __launch_bounds__(256, 3) void conv3x3_mfma(
    const short* __restrict__ in, const short* __restrict__ wmc,
    const short* __restrict__ res, short* __restrict__ out)
{
    __shared__ short sIn[180 * 72];        // 10h x 18w rows, 64 ic + 8 pad
    __shared__ short wLds[2][8][512];      // dbuf x 8 ocT-frags x 1KB

    // T1 XCD swizzle (r6: keeps weights L2-resident per XCD; keep)
    int bid0 = blockIdx.x;
    int bid  = (bid0 & 7) * 256 + (bid0 >> 3);

    int wt = bid & 7, ht = (bid >> 3) & 15, b = bid >> 7;
    int w0 = wt * 16, h0 = ht * 8;
    int tid  = threadIdx.x;
    int lane = tid & 63, wv = tid >> 6;
    int q = lane >> 4, l15 = lane & 15;
    int wr = wv & 1;       // row half
    int wc = wv >> 1;      // oc half

    const short* wb = wmc + b * 147456;

    // per-lane swizzle offsets (bytes)
    int swoff = (lane * 16) ^ (((lane >> 3) & 3) << 4);          // glload src
    int rdoff = l15 * 64 + 16 * (q ^ ((l15 >> 1) & 3));          // bf ds_read

    f32x4 acc[4][4];
    #pragma unroll
    for (int mt = 0; mt < 4; ++mt)
        #pragma unroll
        for (int nt = 0; nt < 4; ++nt)
            acc[mt][nt] = (f32x4){0.f, 0.f, 0.f, 0.f};

    bf16x8 af[2][4];   // pixels (LDS), parity s&1, distance 1
    bf16x8 bf[2][4];   // weights (LDS), parity s&1, same-step read

    // --- weight stage: 8 frags for step (c,tap) into wLds[p]; 2 per wave ---
    auto stageW = [&](int p, int tap, int c) {
        #pragma unroll
        for (int j = 0; j < 2; ++j) {
            int f = wv * 2 + j;
            const short* src = wb + ((tap * 8 + f) * 4 + c) * 512;
            gl_lds16((const short*)((const char*)src + swoff), &wLds[p][f][0]);
        }
    };
    auto ldBF = [&](int p) {
        #pragma unroll
        for (int nt = 0; nt < 4; ++nt)
            bf[p][nt] = *(const bf16x8*)((const char*)&wLds[p][wc * 4 + nt][0] + rdoff);
    };
    auto ldAF = [&](int slot, int tap, int c) {
        int dh = tap / 3, dw = tap - dh * 3;
        #pragma unroll
        for (int mt = 0; mt < 4; ++mt)
            af[slot][mt] = *(const bf16x8*)&sIn[((wr * 4 + mt + dh) * 18 + l15 + dw) * 72
                                                + (c & 1) * 32 + q * 8];
    };
    // input stagers: 180 px rows x (64 ic -> 8 uint4) for the first half,
    // 180 x 4 uint4 per quarter for the mid-loop halves.
    auto stageIn0 = [&]() {
        #pragma unroll
        for (int j = 0; j < 6; ++j) {
            int i = tid + j * 256;
            if (i < 1440) {
                int icg = i & 7, t = i >> 3;
                int wl = t % 18, hl = t / 18;
                int gh = h0 - 1 + hl, gw = w0 - 1 + wl;
                uint4 v = make_uint4(0u, 0u, 0u, 0u);
                if ((unsigned)gh < (unsigned)H && (unsigned)gw < (unsigned)W)
                    v = *(const uint4*)&in[((b * H + gh) * W + gw) * C + icg * 8];
                *(uint4*)&sIn[(hl * 18 + wl) * 72 + icg * 8] = v;
            }
        }
    };
    auto stageInQ = [&](int j, int icbase, int colbase) {
        int i = tid + j * 256;
        if (i < 720) {
            int icg = i & 3, t = i >> 2;
            int wl = t % 18, hl = t / 18;
            int gh = h0 - 1 + hl, gw = w0 - 1 + wl;
            uint4 v = make_uint4(0u, 0u, 0u, 0u);
            if ((unsigned)gh < (unsigned)H && (unsigned)gw < (unsigned)W)
                v = *(const uint4*)&in[((b * H + gh) * W + gw) * C + icbase + icg * 8];
            *(uint4*)&sIn[(hl * 18 + wl) * 72 + colbase + icg * 8] = v;
        }
    };

    // prologue: weights(s=0) async + input ic0-63; barrier drains both.
    stageW(0, 0, 0);
    stageIn0();
    __syncthreads();
    ldAF(0, 0, 0);

    #pragma unroll
    for (int s = 0; s < 36; ++s) {
        int c = s / 9, tap = s % 9;
        (void)c; (void)tap;
        if (s + 1 < 36)
            stageW((s + 1) & 1, (s + 1) % 9, (s + 1) / 9);
        if (s >= 9  && s <= 11) stageInQ(s - 9, 64, 0);    // ic64-95 -> cols 0-31
        if (s >= 18 && s <= 20) stageInQ(s - 18, 96, 32);  // ic96-127 -> cols 32-63
        ldBF(s & 1);
        if (s + 1 < 36) ldAF((s + 1) & 1, (s + 1) % 9, (s + 1) / 9);
        __builtin_amdgcn_s_setprio(1);
        #pragma unroll
        for (int mt = 0; mt < 4; ++mt)
            #pragma unroll
            for (int nt = 0; nt < 4; ++nt)
                acc[mt][nt] = __builtin_amdgcn_mfma_f32_16x16x32_bf16(
                    af[s & 1][mt], bf[s & 1][nt], acc[mt][nt], 0, 0, 0);
        __builtin_amdgcn_s_setprio(0);
        __syncthreads();   // drains glload(s+1) + input ds_writes; pages dbuf
    }

    bool has_res = (res != nullptr);
    #pragma unroll
    for (int mt = 0; mt < 4; ++mt) {
        int h = h0 + wr * 4 + mt;
        #pragma unroll
        for (int nt = 0; nt < 4; ++nt) {
            int oc = wc * 64 + nt * 16 + l15;
            #pragma unroll
            for (int reg = 0; reg < 4; ++reg) {
                int w = w0 + q * 4 + reg;
                int idx = ((b * H + h) * W + w) * C + oc;
                float v = acc[mt][nt][reg];
                if (has_res) v += bs2f(res[idx]);
                v = v >= 0.f ? v : SLOPE * v;
                out[idx] = f2bs(v);
            }
        }
    }
}

// ---------------------------------------------------------------------------
// downconv MFMA — round-2 structure + T5 setprio (warm ~<144 us in r4).
// FROZEN this round to isolate the conv3x3 change.
//  LESSONS (do not regress):
//   r1: +pre[11] T14 staging -> >128 arch VGPR -> scratch spill (WRITE 488MB).
//   r3: 4oh-tile/double-buffer/1-barrier restructure -> FETCH 373MB, 333us.
//   r4: T5 setprio around MFMA cluster: 191 -> <144 us. Keep.
// ---------------------------------------------------------------------------
__global__ __launch_bounds__(256, 2) void downconv_mfma(
    const short* __restrict__ in, const short* __restrict__ dwm,
    const float* __restrict__ db, float* __restrict__ out)
{
    __shared__ short sIn[19 * 2 * 18 * 40];   // 54,720 B

    int bid = blockIdx.x;
    int wt = bid & 3;  bid >>= 2;
    int ht = bid & 7;  bid >>= 3;
    int ot = bid & 1;  bid >>= 1;
    int b  = bid;
    int ow0 = wt * 16, oh0 = ht * 8, oc0 = ot * 128;

    int tid  = threadIdx.x;
    int lane = tid & 63, wv = tid >> 6;
    int q = lane >> 4, l15 = lane & 15;
    int wo = wv & 1;
    int wp = wv >> 1;

    f32x4 acc[4][4];
    #pragma unroll
    for (int mt = 0; mt < 4; ++mt)
        #pragma unroll
        for (int nt = 0; nt < 4; ++nt)
            acc[mt][nt] = (f32x4){0.f, 0.f, 0.f, 0.f};

    int ocTb = ot * 8 + wo * 4;   // this wave's oc-tile base (16-oc units)

    // ---- direct stage of ic-chunk 0 ----
    for (int i = tid; i < 19 * 35 * 4; i += 256) {
        int icg = i & 3;
        int t = i >> 2;
        int wl = t % 35, hl = t / 35;
        int gh = 2 * oh0 - 1 + hl, gw = 2 * ow0 - 1 + wl;
        uint4 v = make_uint4(0u, 0u, 0u, 0u);
        if ((unsigned)gh < (unsigned)H && (unsigned)gw < (unsigned)W)
            v = *(const uint4*)&in[((b * H + gh) * W + gw) * C + icg * 8];
        *(uint4*)&sIn[((hl * 2 + (wl & 1)) * 18 + (wl >> 1)) * 40 + icg * 8] = v;
    }

    bf16x8 af[4][4];   // A ring: slot = (c*16+tap) & 3, filled 3 steps ahead
    bf16x8 bf[2][4];   // B parity: slot = tap & 1

    // A-pipeline prologue: steps 0..2 (c=0, taps 0..2) — no LDS dependence
    #pragma unroll
    for (int s = 0; s < 3; ++s)
        #pragma unroll
        for (int mt = 0; mt < 4; ++mt)
            af[s][mt] = *(const bf16x8*)&dwm[((s * 16 + ocTb + mt) * 4 + 0) * 512
                                             + l15 * 32 + q * 8];

    __syncthreads();

    #pragma unroll 1
    for (int c = 0; c < 4; ++c) {
        // B prologue: tap 0 (dh=0, dw=0)
        #pragma unroll
        for (int nt = 0; nt < 4; ++nt) {
            int hl = 2 * (wp * 4 + nt);
            bf[0][nt] = *(const bf16x8*)&sIn[(hl * 2 * 18 + l15) * 40 + q * 8];
        }

        #pragma unroll
        for (int tap = 0; tap < 16; ++tap) {
            // A prefetch: flattened step s+3 (crosses the c boundary)
            {
                int sp = c * 16 + tap + 3;
                sp = sp < 63 ? sp : 63;          // dummy tail prefetch
                int pc = sp >> 4, pt = sp & 15;
                #pragma unroll
                for (int mt = 0; mt < 4; ++mt)
                    af[(tap + 3) & 3][mt] =
                        *(const bf16x8*)&dwm[((pt * 16 + ocTb + mt) * 4 + pc) * 512
                                             + l15 * 32 + q * 8];
            }
            // B prefetch: tap+1
            {
                int tapn = (tap + 1 < 16) ? tap + 1 : tap;
                int dhn = tapn >> 2, dwn = tapn & 3;
                #pragma unroll
                for (int nt = 0; nt < 4; ++nt) {
                    int hl = 2 * (wp * 4 + nt) + dhn;
                    bf[(tap + 1) & 1][nt] =
                        *(const bf16x8*)&sIn[((hl * 2 + (dwn & 1)) * 18 + l15 + (dwn >> 1)) * 40
                                             + q * 8];
                }
            }
            // compute tap (T5)
            __builtin_amdgcn_s_setprio(1);
            #pragma unroll
            for (int mt = 0; mt < 4; ++mt)
                #pragma unroll
                for (int nt = 0; nt < 4; ++nt)
                    acc[mt][nt] = __builtin_amdgcn_mfma_f32_16x16x32_bf16(
                        af[tap & 3][mt], bf[tap & 1][nt], acc[mt][nt], 0, 0, 0);
            __builtin_amdgcn_s_setprio(0);
        }

        if (c < 3) {
            __syncthreads();                     // all reads of chunk c done
            for (int i = tid; i < 19 * 35 * 4; i += 256) {
                int icg = i & 3;
                int t = i >> 2;
                int wl = t % 35, hl = t / 35;
                int gh = 2 * oh0 - 1 + hl, gw = 2 * ow0 - 1 + wl;
                uint4 v = make_uint4(0u, 0u, 0u, 0u);
                if ((unsigned)gh < (unsigned)H && (unsigned)gw < (unsigned)W)
                    v = *(const uint4*)&in[((b * H + gh) * W + gw) * C
                                           + (c + 1) * 32 + icg * 8];
                *(uint4*)&sIn[((hl * 2 + (wl & 1)) * 18 + (wl >> 1)) * 40 + icg * 8] = v;
            }
            __syncthreads();                     // chunk c+1 visible
        }
    }

    #pragma unroll
    for (int mt = 0; mt < 4; ++mt) {
        #pragma unroll
        for (int reg = 0; reg < 4; ++reg) {
            int oc = oc0 + wo * 64 + mt * 16 + q * 4 + reg;
            float bias = db[oc];
            #pragma unroll
            for (int nt = 0; nt < 4; ++nt) {
                int oh = oh0 + wp * 4 + nt;
                int ow = ow0 + l15;
                out[((b * CO + oc) * HO + oh) * WO + ow] = acc[mt][nt][reg] + bias;
            }
        }
    }
}

// ---------------------------------------------------------------------------
extern "C" void kernel_launch(void* const* d_in, const int* in_sizes, int n_in,
                              void* d_out, int out_size, void* d_ws, size_t ws_size,
                              hipStream_t stream) {
    const float* features = (const float*)d_in[0];
    const float* sm1      = (const float*)d_in[1];   // style_mean1 -> s1
    const float* ss1      = (const float*)d_in[2];   // style_std1  -> s2 (per reference)
    const float* w1       = (const float*)d_in[6];
    const float* w2       = (const float*)d_in[7];
    const float* dw       = (const float*)d_in[8];
    const float* db       = (const float*)d_in[9];
    float* out = (float*)d_out;

    char* ws = (char*)d_ws;
    short* x1  = (short*)ws;                              // 67,108,864 B
    short* x2  = (short*)(ws + 67108864);                 // 67,108,864 B (also fx)
    short* wm  = (short*)(ws + 134217728);                // 9,437,184 B
    short* dwm = (short*)(ws + 143654912);                // 1,048,576 B
    float* dv  = (float*)(ws + 144703488);                // 16,384 B

    demod_kernel    <<<4096, 128, 0, stream>>>(w1, w2, sm1, ss1, dv);
    expand_kernel   <<<18432, 256, 0, stream>>>(w1, w2, sm1, ss1, dv, wm);
    dwexpand_kernel <<<2048, 256, 0, stream>>>(dw, dwm);
    nchw2nhwc_kernel<<<2048, 256, 0, stream>>>(features, x2);
    conv3x3_mfma    <<<2048, 256, 0, stream>>>(x2, wm, nullptr, x1);
    conv3x3_mfma    <<<2048, 256, 0, stream>>>(x1, wm + 16 * 147456, x1, x2);
    downconv_mfma   <<<1024, 256, 0, stream>>>(x2, dwm, db, out);
}

// Round 8
// 537.470 us; speedup vs baseline: 1.1259x; 1.1259x over previous
//
#include <hip/hip_runtime.h>
#include <hip/hip_bf16.h>

constexpr int B  = 16;
constexpr int C  = 128;
constexpr int H  = 128;
constexpr int W  = 128;
constexpr int CO = 256;
constexpr int HO = 64;
constexpr int WO = 64;

#define EPSV   1e-8f
#define SLOPE  0.2f

typedef short bf16x8 __attribute__((ext_vector_type(8)));
typedef float f32x4  __attribute__((ext_vector_type(4)));

__device__ __forceinline__ short f2bs(float v) {
    __hip_bfloat16 h = __float2bfloat16(v);
    return *(short*)&h;
}
__device__ __forceinline__ float bs2f(short s) {
    __hip_bfloat16 h = *(__hip_bfloat16*)&s;
    return __bfloat162float(h);
}

// ---------------------------------------------------------------------------
// demod: d[conv][b][o] = rsqrt(sum_{i,k}(w[o,i,k]*(s[b,i]+1))^2 + eps)
// ---------------------------------------------------------------------------
__global__ __launch_bounds__(128) void demod_kernel(
    const float* __restrict__ w1, const float* __restrict__ w2,
    const float* __restrict__ s1, const float* __restrict__ s2,
    float* __restrict__ d)
{
    int bid  = blockIdx.x;          // conv*2048 + b*128 + o
    int conv = bid >> 11;
    int b    = (bid >> 7) & 15;
    int o    = bid & 127;
    const float* w = conv ? w2 : w1;
    const float* s = conv ? s2 : s1;
    int i = threadIdx.x;
    float sv = s[b * C + i] + 1.0f;
    const float* wp = w + (o * C + i) * 9;
    float sum = 0.f;
    #pragma unroll
    for (int k = 0; k < 9; ++k) { float t = wp[k] * sv; sum += t * t; }
    #pragma unroll
    for (int off = 32; off; off >>= 1) sum += __shfl_down(sum, off);
    __shared__ float red[2];
    if ((threadIdx.x & 63) == 0) red[threadIdx.x >> 6] = sum;
    __syncthreads();
    if (threadIdx.x == 0) d[bid] = rsqrtf(red[0] + red[1] + EPSV);
}

// ---------------------------------------------------------------------------
// expand -> wave-coalesced B-fragment tiling (round-8: 4 ic per thread,
// float4 style load + 8B packed store; G13 — scalar bf16 stores were the
// prep-stage inefficiency).
// wm[cb][tap][ocT=oc>>4][icC=ic>>5][(oc&15)*32 + (ic&31)]   (bf16)
// ---------------------------------------------------------------------------
__global__ __launch_bounds__(256) void expand_kernel(
    const float* __restrict__ w1, const float* __restrict__ w2,
    const float* __restrict__ s1, const float* __restrict__ s2,
    const float* __restrict__ d, short* __restrict__ wm)
{
    int idx = blockIdx.x * 256 + threadIdx.x;   // 288*128*32 = 1,179,648
    int icq = idx & 31;                          // ic quad index
    int oc  = (idx >> 5) & 127;
    int t   = idx >> 12;                         // cb*9+tap, < 288
    int tap = t % 9;
    int cb  = t / 9;                             // conv*16+b
    int b   = cb & 15;
    int conv= cb >> 4;
    const float* w = conv ? w2 : w1;
    const float* s = conv ? s2 : s1;
    int ic0 = icq * 4;

    float4 sv = *(const float4*)&s[b * C + ic0];
    float dv = d[(conv * B + b) * C + oc];
    const float* wp = w + (oc * C + ic0) * 9 + tap;

    short vs[4];
    vs[0] = f2bs(wp[ 0] * (sv.x + 1.0f) * dv);
    vs[1] = f2bs(wp[ 9] * (sv.y + 1.0f) * dv);
    vs[2] = f2bs(wp[18] * (sv.z + 1.0f) * dv);
    vs[3] = f2bs(wp[27] * (sv.w + 1.0f) * dv);

    int dst = cb * 147456
            + ((tap * 8 + (oc >> 4)) * 4 + (ic0 >> 5)) * 512
            + (oc & 15) * 32 + (ic0 & 31);
    *(uint2*)&wm[dst] = *(uint2*)vs;
}

// ---------------------------------------------------------------------------
// dwexpand: dwm[tap][ocT=oc>>4 (16)][icC=ic>>5 (4)][(oc&15)*32+(ic&31)]
// ---------------------------------------------------------------------------
__global__ __launch_bounds__(256) void dwexpand_kernel(
    const float* __restrict__ dw, short* __restrict__ dwm)
{
    int idx = blockIdx.x * 256 + threadIdx.x;   // 16*256*128 = 524288
    int ic  = idx & 127;
    int oc  = (idx >> 7) & 255;
    int tap = idx >> 15;
    int dst = ((tap * 16 + (oc >> 4)) * 4 + (ic >> 5)) * 512
            + (oc & 15) * 32 + (ic & 31);
    dwm[dst] = f2bs(dw[(oc * C + ic) * 16 + tap]);
}

// ---------------------------------------------------------------------------
// nchw(f32) -> nhwc(bf16) transpose of features.
// ---------------------------------------------------------------------------
__global__ __launch_bounds__(256) void nchw2nhwc_kernel(
    const float* __restrict__ in, short* __restrict__ out)
{
    __shared__ short s[128 * 136];
    int bid = blockIdx.x;                   // b*128 + h
    int h = bid & 127, b = bid >> 7;
    int tid = threadIdx.x;
    for (int i = tid; i < 128 * 32; i += 256) {
        int w4 = i & 31, ic = i >> 5;
        float4 v = *(const float4*)&in[((b * C + ic) * H + h) * W + w4 * 4];
        s[(w4 * 4 + 0) * 136 + ic] = f2bs(v.x);
        s[(w4 * 4 + 1) * 136 + ic] = f2bs(v.y);
        s[(w4 * 4 + 2) * 136 + ic] = f2bs(v.z);
        s[(w4 * 4 + 3) * 136 + ic] = f2bs(v.w);
    }
    __syncthreads();
    for (int i = tid; i < 128 * 16; i += 256) {
        int icg = i & 15, w = i >> 4;
        *(uint4*)&out[((b * H + h) * W + w) * C + icg * 8] =
            *(uint4*)&s[w * 136 + icg * 8];
    }
}

// ---------------------------------------------------------------------------
// conv3x3 MFMA implicit GEMM — r6 configuration (best verified: 144 us).
// T1 XCD swizzle + 36-step unrolled K loop + bf ring-3 + af dbuf + T5.
// LESSONS (do not regress):
//  r5: bf ring-3 vs ring-2 = null (latency not distance-coverable).
//  r6: T1 swizzle: FETCH -30%, time flat -> weight-fetch not the limiter.
//  r7: m97-style per-step barrier pipeline = REGRESS (144->167, MfmaUtil
//      18%): 36 vmcnt(0)-draining barriers not amortized at 16 MFMA/step.
//  The r6 streaming-weights form is the local optimum for this step shape.
// ---------------------------------------------------------------------------
__global__ __launch_bounds__(256, 3) void conv3x3_mfma(
    const short* __restrict__ in, const short* __restrict__ wmc,
    const short* __restrict__ res, short* __restrict__ out)
{
    __shared__ short sIn[10 * 18 * 136];   // 48,960 B

    // T1: XCD-aware swizzle. xcd = hw_bid % 8; each XCD gets a contiguous
    // 256-block chunk (= 2 batch images) -> weights L2-resident per XCD.
    int bid0 = blockIdx.x;
    int bid  = (bid0 & 7) * 256 + (bid0 >> 3);

    int wt = bid & 7, ht = (bid >> 3) & 15, b = bid >> 7;
    int w0 = wt * 16, h0 = ht * 8;
    int tid  = threadIdx.x;
    int lane = tid & 63, wv = tid >> 6;
    int q = lane >> 4, l15 = lane & 15;
    int wr = wv & 1;       // row half
    int wc = wv >> 1;      // oc half

    for (int i = tid; i < 10 * 18 * 16; i += 256) {
        int icg = i & 15;
        int t = i >> 4;
        int wl = t % 18, hl = t / 18;
        int gh = h0 - 1 + hl, gw = w0 - 1 + wl;
        uint4 v = make_uint4(0u, 0u, 0u, 0u);
        if ((unsigned)gh < (unsigned)H && (unsigned)gw < (unsigned)W)
            v = *(const uint4*)&in[((b * H + gh) * W + gw) * C + icg * 8];
        *(uint4*)&sIn[(hl * 18 + wl) * 136 + icg * 8] = v;
    }
    __syncthreads();

    const short* wb = wmc + b * 147456;

    f32x4 acc[4][4];
    #pragma unroll
    for (int mt = 0; mt < 4; ++mt)
        #pragma unroll
        for (int nt = 0; nt < 4; ++nt)
            acc[mt][nt] = (f32x4){0.f, 0.f, 0.f, 0.f};

    bf16x8 af[2][4];   // pixels (LDS), parity s&1, distance 1
    bf16x8 bf[3][4];   // weights (global), ring s%3, distance 2

    // K-step s = tap*4 + c  (tap = s>>2 since 36 = 9*4, c = s&3)
    auto ldAF = [&](int slot, int tap, int c) {
        int dh = tap / 3, dw = tap - dh * 3;
        #pragma unroll
        for (int mt = 0; mt < 4; ++mt)
            af[slot][mt] = *(const bf16x8*)&sIn[((wr * 4 + mt + dh) * 18 + l15 + dw) * 136
                                                + c * 32 + q * 8];
    };
    auto ldBF = [&](int slot, int tap, int c) {
        #pragma unroll
        for (int nt = 0; nt < 4; ++nt)
            bf[slot][nt] = *(const bf16x8*)&wb[((tap * 8 + wc * 4 + nt) * 4 + c) * 512
                                               + l15 * 32 + q * 8];
    };

    // prologue: af step 0; bf steps 0,1
    ldAF(0, 0, 0);
    ldBF(0, 0, 0);
    ldBF(1, 0, 1);

    #pragma unroll
    for (int s = 0; s < 36; ++s) {
        // issue global (long-latency) prefetch first: step s+2 into ring slot
        int s2 = (s + 2 < 36) ? s + 2 : s;       // dummy at tail
        ldBF((s + 2) % 3, s2 >> 2, s2 & 3);
        // LDS prefetch: step s+1
        int s1 = (s + 1 < 36) ? s + 1 : s;       // dummy at tail
        ldAF((s + 1) & 1, s1 >> 2, s1 & 3);
        // compute step s (T5: favor MFMA waves while others stage/load)
        __builtin_amdgcn_s_setprio(1);
        #pragma unroll
        for (int mt = 0; mt < 4; ++mt)
            #pragma unroll
            for (int nt = 0; nt < 4; ++nt)
                acc[mt][nt] = __builtin_amdgcn_mfma_f32_16x16x32_bf16(
                    af[s & 1][mt], bf[s % 3][nt], acc[mt][nt], 0, 0, 0);
        __builtin_amdgcn_s_setprio(0);
    }

    bool has_res = (res != nullptr);
    #pragma unroll
    for (int mt = 0; mt < 4; ++mt) {
        int h = h0 + wr * 4 + mt;
        #pragma unroll
        for (int nt = 0; nt < 4; ++nt) {
            int oc = wc * 64 + nt * 16 + l15;
            #pragma unroll
            for (int reg = 0; reg < 4; ++reg) {
                int w = w0 + q * 4 + reg;
                int idx = ((b * H + h) * W + w) * C + oc;
                float v = acc[mt][nt][reg];
                if (has_res) v += bs2f(res[idx]);
                v = v >= 0.f ? v : SLOPE * v;
                out[idx] = f2bs(v);
            }
        }
    }
}

// ---------------------------------------------------------------------------
// downconv MFMA — round-2 structure + T5 setprio (warm <144 us since r4).
//  LESSONS (do not regress):
//   r1: +pre[11] T14 staging -> >128 arch VGPR -> scratch spill (WRITE 488MB).
//   r3: 4oh-tile/double-buffer/1-barrier restructure -> FETCH 373MB, 333us.
//   r4: T5 setprio around MFMA cluster: 191 -> <144 us. Keep.
// ---------------------------------------------------------------------------
__global__ __launch_bounds__(256, 2) void downconv_mfma(
    const short* __restrict__ in, const short* __restrict__ dwm,
    const float* __restrict__ db, float* __restrict__ out)
{
    __shared__ short sIn[19 * 2 * 18 * 40];   // 54,720 B

    int bid = blockIdx.x;
    int wt = bid & 3;  bid >>= 2;
    int ht = bid & 7;  bid >>= 3;
    int ot = bid & 1;  bid >>= 1;
    int b  = bid;
    int ow0 = wt * 16, oh0 = ht * 8, oc0 = ot * 128;

    int tid  = threadIdx.x;
    int lane = tid & 63, wv = tid >> 6;
    int q = lane >> 4, l15 = lane & 15;
    int wo = wv & 1;
    int wp = wv >> 1;

    f32x4 acc[4][4];
    #pragma unroll
    for (int mt = 0; mt < 4; ++mt)
        #pragma unroll
        for (int nt = 0; nt < 4; ++nt)
            acc[mt][nt] = (f32x4){0.f, 0.f, 0.f, 0.f};

    int ocTb = ot * 8 + wo * 4;   // this wave's oc-tile base (16-oc units)

    // ---- direct stage of ic-chunk 0 ----
    for (int i = tid; i < 19 * 35 * 4; i += 256) {
        int icg = i & 3;
        int t = i >> 2;
        int wl = t % 35, hl = t / 35;
        int gh = 2 * oh0 - 1 + hl, gw = 2 * ow0 - 1 + wl;
        uint4 v = make_uint4(0u, 0u, 0u, 0u);
        if ((unsigned)gh < (unsigned)H && (unsigned)gw < (unsigned)W)
            v = *(const uint4*)&in[((b * H + gh) * W + gw) * C + icg * 8];
        *(uint4*)&sIn[((hl * 2 + (wl & 1)) * 18 + (wl >> 1)) * 40 + icg * 8] = v;
    }

    bf16x8 af[4][4];   // A ring: slot = (c*16+tap) & 3, filled 3 steps ahead
    bf16x8 bf[2][4];   // B parity: slot = tap & 1

    // A-pipeline prologue: steps 0..2 (c=0, taps 0..2) — no LDS dependence
    #pragma unroll
    for (int s = 0; s < 3; ++s)
        #pragma unroll
        for (int mt = 0; mt < 4; ++mt)
            af[s][mt] = *(const bf16x8*)&dwm[((s * 16 + ocTb + mt) * 4 + 0) * 512
                                             + l15 * 32 + q * 8];

    __syncthreads();

    #pragma unroll 1
    for (int c = 0; c < 4; ++c) {
        // B prologue: tap 0 (dh=0, dw=0)
        #pragma unroll
        for (int nt = 0; nt < 4; ++nt) {
            int hl = 2 * (wp * 4 + nt);
            bf[0][nt] = *(const bf16x8*)&sIn[(hl * 2 * 18 + l15) * 40 + q * 8];
        }

        #pragma unroll
        for (int tap = 0; tap < 16; ++tap) {
            // A prefetch: flattened step s+3 (crosses the c boundary)
            {
                int sp = c * 16 + tap + 3;
                sp = sp < 63 ? sp : 63;          // dummy tail prefetch
                int pc = sp >> 4, pt = sp & 15;
                #pragma unroll
                for (int mt = 0; mt < 4; ++mt)
                    af[(tap + 3) & 3][mt] =
                        *(const bf16x8*)&dwm[((pt * 16 + ocTb + mt) * 4 + pc) * 512
                                             + l15 * 32 + q * 8];
            }
            // B prefetch: tap+1
            {
                int tapn = (tap + 1 < 16) ? tap + 1 : tap;
                int dhn = tapn >> 2, dwn = tapn & 3;
                #pragma unroll
                for (int nt = 0; nt < 4; ++nt) {
                    int hl = 2 * (wp * 4 + nt) + dhn;
                    bf[(tap + 1) & 1][nt] =
                        *(const bf16x8*)&sIn[((hl * 2 + (dwn & 1)) * 18 + l15 + (dwn >> 1)) * 40
                                             + q * 8];
                }
            }
            // compute tap (T5)
            __builtin_amdgcn_s_setprio(1);
            #pragma unroll
            for (int mt = 0; mt < 4; ++mt)
                #pragma unroll
                for (int nt = 0; nt < 4; ++nt)
                    acc[mt][nt] = __builtin_amdgcn_mfma_f32_16x16x32_bf16(
                        af[tap & 3][mt], bf[tap & 1][nt], acc[mt][nt], 0, 0, 0);
            __builtin_amdgcn_s_setprio(0);
        }

        if (c < 3) {
            __syncthreads();                     // all reads of chunk c done
            for (int i = tid; i < 19 * 35 * 4; i += 256) {
                int icg = i & 3;
                int t = i >> 2;
                int wl = t % 35, hl = t / 35;
                int gh = 2 * oh0 - 1 + hl, gw = 2 * ow0 - 1 + wl;
                uint4 v = make_uint4(0u, 0u, 0u, 0u);
                if ((unsigned)gh < (unsigned)H && (unsigned)gw < (unsigned)W)
                    v = *(const uint4*)&in[((b * H + gh) * W + gw) * C
                                           + (c + 1) * 32 + icg * 8];
                *(uint4*)&sIn[((hl * 2 + (wl & 1)) * 18 + (wl >> 1)) * 40 + icg * 8] = v;
            }
            __syncthreads();                     // chunk c+1 visible
        }
    }

    #pragma unroll
    for (int mt = 0; mt < 4; ++mt) {
        #pragma unroll
        for (int reg = 0; reg < 4; ++reg) {
            int oc = oc0 + wo * 64 + mt * 16 + q * 4 + reg;
            float bias = db[oc];
            #pragma unroll
            for (int nt = 0; nt < 4; ++nt) {
                int oh = oh0 + wp * 4 + nt;
                int ow = ow0 + l15;
                out[((b * CO + oc) * HO + oh) * WO + ow] = acc[mt][nt][reg] + bias;
            }
        }
    }
}

// ---------------------------------------------------------------------------
extern "C" void kernel_launch(void* const* d_in, const int* in_sizes, int n_in,
                              void* d_out, int out_size, void* d_ws, size_t ws_size,
                              hipStream_t stream) {
    const float* features = (const float*)d_in[0];
    const float* sm1      = (const float*)d_in[1];   // style_mean1 -> s1
    const float* ss1      = (const float*)d_in[2];   // style_std1  -> s2 (per reference)
    const float* w1       = (const float*)d_in[6];
    const float* w2       = (const float*)d_in[7];
    const float* dw       = (const float*)d_in[8];
    const float* db       = (const float*)d_in[9];
    float* out = (float*)d_out;

    char* ws = (char*)d_ws;
    short* x1  = (short*)ws;                              // 67,108,864 B
    short* x2  = (short*)(ws + 67108864);                 // 67,108,864 B (also fx)
    short* wm  = (short*)(ws + 134217728);                // 9,437,184 B
    short* dwm = (short*)(ws + 143654912);                // 1,048,576 B
    float* dv  = (float*)(ws + 144703488);                // 16,384 B

    demod_kernel    <<<4096, 128, 0, stream>>>(w1, w2, sm1, ss1, dv);
    expand_kernel   <<<4608, 256, 0, stream>>>(w1, w2, sm1, ss1, dv, wm);
    dwexpand_kernel <<<2048, 256, 0, stream>>>(dw, dwm);
    nchw2nhwc_kernel<<<2048, 256, 0, stream>>>(features, x2);
    conv3x3_mfma    <<<2048, 256, 0, stream>>>(x2, wm, nullptr, x1);
    conv3x3_mfma    <<<2048, 256, 0, stream>>>(x1, wm + 16 * 147456, x1, x2);
    downconv_mfma   <<<1024, 256, 0, stream>>>(x2, dwm, db, out);
}

// Round 9
// 505.933 us; speedup vs baseline: 1.1960x; 1.0623x over previous
//
#include <hip/hip_runtime.h>
#include <hip/hip_bf16.h>

constexpr int B  = 16;
constexpr int C  = 128;
constexpr int H  = 128;
constexpr int W  = 128;
constexpr int CO = 256;
constexpr int HO = 64;
constexpr int WO = 64;

#define EPSV   1e-8f
#define SLOPE  0.2f

typedef short bf16x8 __attribute__((ext_vector_type(8)));
typedef float f32x4  __attribute__((ext_vector_type(4)));

__device__ __forceinline__ short f2bs(float v) {
    __hip_bfloat16 h = __float2bfloat16(v);
    return *(short*)&h;
}
__device__ __forceinline__ float bs2f(short s) {
    __hip_bfloat16 h = *(__hip_bfloat16*)&s;
    return __bfloat162float(h);
}

// ---------------------------------------------------------------------------
// demod: d[conv][b][o] = rsqrt(sum_{i,k}(w[o,i,k]*(s[b,i]+1))^2 + eps)
// ---------------------------------------------------------------------------
__global__ __launch_bounds__(128) void demod_kernel(
    const float* __restrict__ w1, const float* __restrict__ w2,
    const float* __restrict__ s1, const float* __restrict__ s2,
    float* __restrict__ d)
{
    int bid  = blockIdx.x;          // conv*2048 + b*128 + o
    int conv = bid >> 11;
    int b    = (bid >> 7) & 15;
    int o    = bid & 127;
    const float* w = conv ? w2 : w1;
    const float* s = conv ? s2 : s1;
    int i = threadIdx.x;
    float sv = s[b * C + i] + 1.0f;
    const float* wp = w + (o * C + i) * 9;
    float sum = 0.f;
    #pragma unroll
    for (int k = 0; k < 9; ++k) { float t = wp[k] * sv; sum += t * t; }
    #pragma unroll
    for (int off = 32; off; off >>= 1) sum += __shfl_down(sum, off);
    __shared__ float red[2];
    if ((threadIdx.x & 63) == 0) red[threadIdx.x >> 6] = sum;
    __syncthreads();
    if (threadIdx.x == 0) d[bid] = rsqrtf(red[0] + red[1] + EPSV);
}

// ---------------------------------------------------------------------------
// expand -> wave-coalesced B-fragment tiling (r8: 4 ic per thread,
// float4 style load + 8B packed store).
// wm[cb][tap][ocT=oc>>4][icC=ic>>5][(oc&15)*32 + (ic&31)]   (bf16)
// ---------------------------------------------------------------------------
__global__ __launch_bounds__(256) void expand_kernel(
    const float* __restrict__ w1, const float* __restrict__ w2,
    const float* __restrict__ s1, const float* __restrict__ s2,
    const float* __restrict__ d, short* __restrict__ wm)
{
    int idx = blockIdx.x * 256 + threadIdx.x;   // 288*128*32 = 1,179,648
    int icq = idx & 31;                          // ic quad index
    int oc  = (idx >> 5) & 127;
    int t   = idx >> 12;                         // cb*9+tap, < 288
    int tap = t % 9;
    int cb  = t / 9;                             // conv*16+b
    int b   = cb & 15;
    int conv= cb >> 4;
    const float* w = conv ? w2 : w1;
    const float* s = conv ? s2 : s1;
    int ic0 = icq * 4;

    float4 sv = *(const float4*)&s[b * C + ic0];
    float dv = d[(conv * B + b) * C + oc];
    const float* wp = w + (oc * C + ic0) * 9 + tap;

    short vs[4];
    vs[0] = f2bs(wp[ 0] * (sv.x + 1.0f) * dv);
    vs[1] = f2bs(wp[ 9] * (sv.y + 1.0f) * dv);
    vs[2] = f2bs(wp[18] * (sv.z + 1.0f) * dv);
    vs[3] = f2bs(wp[27] * (sv.w + 1.0f) * dv);

    int dst = cb * 147456
            + ((tap * 8 + (oc >> 4)) * 4 + (ic0 >> 5)) * 512
            + (oc & 15) * 32 + (ic0 & 31);
    *(uint2*)&wm[dst] = *(uint2*)vs;
}

// ---------------------------------------------------------------------------
// dwexpand: dwm[tap][ocT=oc>>4 (16)][icC=ic>>5 (4)][(oc&15)*32+(ic&31)]
// ---------------------------------------------------------------------------
__global__ __launch_bounds__(256) void dwexpand_kernel(
    const float* __restrict__ dw, short* __restrict__ dwm)
{
    int idx = blockIdx.x * 256 + threadIdx.x;   // 16*256*128 = 524288
    int ic  = idx & 127;
    int oc  = (idx >> 7) & 255;
    int tap = idx >> 15;
    int dst = ((tap * 16 + (oc >> 4)) * 4 + (ic >> 5)) * 512
            + (oc & 15) * 32 + (ic & 31);
    dwm[dst] = f2bs(dw[(oc * C + ic) * 16 + tap]);
}

// ---------------------------------------------------------------------------
// nchw(f32) -> nhwc(bf16) transpose of features.
// ---------------------------------------------------------------------------
__global__ __launch_bounds__(256) void nchw2nhwc_kernel(
    const float* __restrict__ in, short* __restrict__ out)
{
    __shared__ short s[128 * 136];
    int bid = blockIdx.x;                   // b*128 + h
    int h = bid & 127, b = bid >> 7;
    int tid = threadIdx.x;
    for (int i = tid; i < 128 * 32; i += 256) {
        int w4 = i & 31, ic = i >> 5;
        float4 v = *(const float4*)&in[((b * C + ic) * H + h) * W + w4 * 4];
        s[(w4 * 4 + 0) * 136 + ic] = f2bs(v.x);
        s[(w4 * 4 + 1) * 136 + ic] = f2bs(v.y);
        s[(w4 * 4 + 2) * 136 + ic] = f2bs(v.z);
        s[(w4 * 4 + 3) * 136 + ic] = f2bs(v.w);
    }
    __syncthreads();
    for (int i = tid; i < 128 * 16; i += 256) {
        int icg = i & 15, w = i >> 4;
        *(uint4*)&out[((b * H + h) * W + w) * C + icg * 8] =
            *(uint4*)&s[w * 136 + icg * 8];
    }
}

// ---------------------------------------------------------------------------
// conv3x3 MFMA implicit GEMM — round-9 retile: wave = 128px x 32oc.
// EVIDENCE: conv3x3 pinned 142-145us across FIVE variants (r4-r8); per-SIMD
// MFMA busy ~6.5%, HBM 13%, L2 ~12%, all idle -> latency stall. Invariant
// across variants: 4 global dwordx4/wave/step with wr-pair waves loading
// IDENTICAL bf frags (2x duplicated VMEM). This round halves per-wave global
// loads (2/step) and dedups weight traffic (each frag read by exactly 1 wave).
// af moves to 8 frags/step from LDS. K-loop skeleton/swizzle/setprio kept.
// Register audit: acc[8][2]=64 + af[2][8]=64 + bf[2][2]=16 + misc~25 = 169
// unified <= 170 -> 3 waves/SIMD (launch_bounds(256,3)); LDS 48.9KB -> 3 blk/CU.
// LESSONS: r5 ring-3 null (bf ring-2 here); r7 per-step barriers regress.
// TRIPWIRES: WRITE>100MB or VGPR>120 = spill -> revert to r8 form.
// NULL READING: dur 142+-3 flat -> per-wave-VMEM theory falsified.
// ---------------------------------------------------------------------------
__global__ __launch_bounds__(256, 3) void conv3x3_mfma(
    const short* __restrict__ in, const short* __restrict__ wmc,
    const short* __restrict__ res, short* __restrict__ out)
{
    __shared__ short sIn[10 * 18 * 136];   // 48,960 B

    // T1: XCD-aware swizzle (r6: weights L2-resident per XCD; keep).
    int bid0 = blockIdx.x;
    int bid  = (bid0 & 7) * 256 + (bid0 >> 3);

    int wt = bid & 7, ht = (bid >> 3) & 15, b = bid >> 7;
    int w0 = wt * 16, h0 = ht * 8;
    int tid  = threadIdx.x;
    int lane = tid & 63, wv = tid >> 6;
    int q = lane >> 4, l15 = lane & 15;

    for (int i = tid; i < 10 * 18 * 16; i += 256) {
        int icg = i & 15;
        int t = i >> 4;
        int wl = t % 18, hl = t / 18;
        int gh = h0 - 1 + hl, gw = w0 - 1 + wl;
        uint4 v = make_uint4(0u, 0u, 0u, 0u);
        if ((unsigned)gh < (unsigned)H && (unsigned)gw < (unsigned)W)
            v = *(const uint4*)&in[((b * H + gh) * W + gw) * C + icg * 8];
        *(uint4*)&sIn[(hl * 18 + wl) * 136 + icg * 8] = v;
    }
    __syncthreads();

    const short* wb = wmc + b * 147456;

    f32x4 acc[8][2];
    #pragma unroll
    for (int mt = 0; mt < 8; ++mt)
        #pragma unroll
        for (int nt = 0; nt < 2; ++nt)
            acc[mt][nt] = (f32x4){0.f, 0.f, 0.f, 0.f};

    bf16x8 af[2][8];   // pixels (LDS), parity s&1, distance 1; 8 h-rows
    bf16x8 bf[2][2];   // weights (global), parity s&1, distance 1; 2 oc-tiles

    // K-step s = tap*4 + c  (tap = s>>2, c = s&3)
    auto ldAF = [&](int slot, int tap, int c) {
        int dh = tap / 3, dw = tap - dh * 3;
        #pragma unroll
        for (int mt = 0; mt < 8; ++mt)
            af[slot][mt] = *(const bf16x8*)&sIn[((mt + dh) * 18 + l15 + dw) * 136
                                                + c * 32 + q * 8];
    };
    auto ldBF = [&](int slot, int tap, int c) {
        #pragma unroll
        for (int nt = 0; nt < 2; ++nt)
            bf[slot][nt] = *(const bf16x8*)&wb[((tap * 8 + wv * 2 + nt) * 4 + c) * 512
                                               + l15 * 32 + q * 8];
    };

    // prologue: step 0 operands
    ldAF(0, 0, 0);
    ldBF(0, 0, 0);

    #pragma unroll
    for (int s = 0; s < 36; ++s) {
        // prefetch step s+1 (global first: longer latency)
        int s1 = (s + 1 < 36) ? s + 1 : s;       // dummy at tail
        ldBF((s + 1) & 1, s1 >> 2, s1 & 3);
        ldAF((s + 1) & 1, s1 >> 2, s1 & 3);
        // compute step s (T5)
        __builtin_amdgcn_s_setprio(1);
        #pragma unroll
        for (int mt = 0; mt < 8; ++mt)
            #pragma unroll
            for (int nt = 0; nt < 2; ++nt)
                acc[mt][nt] = __builtin_amdgcn_mfma_f32_16x16x32_bf16(
                    af[s & 1][mt], bf[s & 1][nt], acc[mt][nt], 0, 0, 0);
        __builtin_amdgcn_s_setprio(0);
    }

    bool has_res = (res != nullptr);
    #pragma unroll
    for (int mt = 0; mt < 8; ++mt) {
        int h = h0 + mt;
        #pragma unroll
        for (int nt = 0; nt < 2; ++nt) {
            int oc = wv * 32 + nt * 16 + l15;
            #pragma unroll
            for (int reg = 0; reg < 4; ++reg) {
                int w = w0 + q * 4 + reg;
                int idx = ((b * H + h) * W + w) * C + oc;
                float v = acc[mt][nt][reg];
                if (has_res) v += bs2f(res[idx]);
                v = v >= 0.f ? v : SLOPE * v;
                out[idx] = f2bs(v);
            }
        }
    }
}

// ---------------------------------------------------------------------------
// downconv MFMA — round-2 structure + T5 setprio (warm <144 us since r4).
// FROZEN.  LESSONS (do not regress):
//   r1: +pre[11] T14 staging -> >128 arch VGPR -> scratch spill (WRITE 488MB).
//   r3: 4oh-tile/double-buffer/1-barrier restructure -> FETCH 373MB, 333us.
//   r4: T5 setprio around MFMA cluster: 191 -> <144 us. Keep.
// ---------------------------------------------------------------------------
__global__ __launch_bounds__(256, 2) void downconv_mfma(
    const short* __restrict__ in, const short* __restrict__ dwm,
    const float* __restrict__ db, float* __restrict__ out)
{
    __shared__ short sIn[19 * 2 * 18 * 40];   // 54,720 B

    int bid = blockIdx.x;
    int wt = bid & 3;  bid >>= 2;
    int ht = bid & 7;  bid >>= 3;
    int ot = bid & 1;  bid >>= 1;
    int b  = bid;
    int ow0 = wt * 16, oh0 = ht * 8, oc0 = ot * 128;

    int tid  = threadIdx.x;
    int lane = tid & 63, wv = tid >> 6;
    int q = lane >> 4, l15 = lane & 15;
    int wo = wv & 1;
    int wp = wv >> 1;

    f32x4 acc[4][4];
    #pragma unroll
    for (int mt = 0; mt < 4; ++mt)
        #pragma unroll
        for (int nt = 0; nt < 4; ++nt)
            acc[mt][nt] = (f32x4){0.f, 0.f, 0.f, 0.f};

    int ocTb = ot * 8 + wo * 4;   // this wave's oc-tile base (16-oc units)

    // ---- direct stage of ic-chunk 0 ----
    for (int i = tid; i < 19 * 35 * 4; i += 256) {
        int icg = i & 3;
        int t = i >> 2;
        int wl = t % 35, hl = t / 35;
        int gh = 2 * oh0 - 1 + hl, gw = 2 * ow0 - 1 + wl;
        uint4 v = make_uint4(0u, 0u, 0u, 0u);
        if ((unsigned)gh < (unsigned)H && (unsigned)gw < (unsigned)W)
            v = *(const uint4*)&in[((b * H + gh) * W + gw) * C + icg * 8];
        *(uint4*)&sIn[((hl * 2 + (wl & 1)) * 18 + (wl >> 1)) * 40 + icg * 8] = v;
    }

    bf16x8 af[4][4];   // A ring: slot = (c*16+tap) & 3, filled 3 steps ahead
    bf16x8 bf[2][4];   // B parity: slot = tap & 1

    // A-pipeline prologue: steps 0..2 (c=0, taps 0..2) — no LDS dependence
    #pragma unroll
    for (int s = 0; s < 3; ++s)
        #pragma unroll
        for (int mt = 0; mt < 4; ++mt)
            af[s][mt] = *(const bf16x8*)&dwm[((s * 16 + ocTb + mt) * 4 + 0) * 512
                                             + l15 * 32 + q * 8];

    __syncthreads();

    #pragma unroll 1
    for (int c = 0; c < 4; ++c) {
        // B prologue: tap 0 (dh=0, dw=0)
        #pragma unroll
        for (int nt = 0; nt < 4; ++nt) {
            int hl = 2 * (wp * 4 + nt);
            bf[0][nt] = *(const bf16x8*)&sIn[(hl * 2 * 18 + l15) * 40 + q * 8];
        }

        #pragma unroll
        for (int tap = 0; tap < 16; ++tap) {
            // A prefetch: flattened step s+3 (crosses the c boundary)
            {
                int sp = c * 16 + tap + 3;
                sp = sp < 63 ? sp : 63;          // dummy tail prefetch
                int pc = sp >> 4, pt = sp & 15;
                #pragma unroll
                for (int mt = 0; mt < 4; ++mt)
                    af[(tap + 3) & 3][mt] =
                        *(const bf16x8*)&dwm[((pt * 16 + ocTb + mt) * 4 + pc) * 512
                                             + l15 * 32 + q * 8];
            }
            // B prefetch: tap+1
            {
                int tapn = (tap + 1 < 16) ? tap + 1 : tap;
                int dhn = tapn >> 2, dwn = tapn & 3;
                #pragma unroll
                for (int nt = 0; nt < 4; ++nt) {
                    int hl = 2 * (wp * 4 + nt) + dhn;
                    bf[(tap + 1) & 1][nt] =
                        *(const bf16x8*)&sIn[((hl * 2 + (dwn & 1)) * 18 + l15 + (dwn >> 1)) * 40
                                             + q * 8];
                }
            }
            // compute tap (T5)
            __builtin_amdgcn_s_setprio(1);
            #pragma unroll
            for (int mt = 0; mt < 4; ++mt)
                #pragma unroll
                for (int nt = 0; nt < 4; ++nt)
                    acc[mt][nt] = __builtin_amdgcn_mfma_f32_16x16x32_bf16(
                        af[tap & 3][mt], bf[tap & 1][nt], acc[mt][nt], 0, 0, 0);
            __builtin_amdgcn_s_setprio(0);
        }

        if (c < 3) {
            __syncthreads();                     // all reads of chunk c done
            for (int i = tid; i < 19 * 35 * 4; i += 256) {
                int icg = i & 3;
                int t = i >> 2;
                int wl = t % 35, hl = t / 35;
                int gh = 2 * oh0 - 1 + hl, gw = 2 * ow0 - 1 + wl;
                uint4 v = make_uint4(0u, 0u, 0u, 0u);
                if ((unsigned)gh < (unsigned)H && (unsigned)gw < (unsigned)W)
                    v = *(const uint4*)&in[((b * H + gh) * W + gw) * C
                                           + (c + 1) * 32 + icg * 8];
                *(uint4*)&sIn[((hl * 2 + (wl & 1)) * 18 + (wl >> 1)) * 40 + icg * 8] = v;
            }
            __syncthreads();                     // chunk c+1 visible
        }
    }

    #pragma unroll
    for (int mt = 0; mt < 4; ++mt) {
        #pragma unroll
        for (int reg = 0; reg < 4; ++reg) {
            int oc = oc0 + wo * 64 + mt * 16 + q * 4 + reg;
            float bias = db[oc];
            #pragma unroll
            for (int nt = 0; nt < 4; ++nt) {
                int oh = oh0 + wp * 4 + nt;
                int ow = ow0 + l15;
                out[((b * CO + oc) * HO + oh) * WO + ow] = acc[mt][nt][reg] + bias;
            }
        }
    }
}

// ---------------------------------------------------------------------------
extern "C" void kernel_launch(void* const* d_in, const int* in_sizes, int n_in,
                              void* d_out, int out_size, void* d_ws, size_t ws_size,
                              hipStream_t stream) {
    const float* features = (const float*)d_in[0];
    const float* sm1      = (const float*)d_in[1];   // style_mean1 -> s1
    const float* ss1      = (const float*)d_in[2];   // style_std1  -> s2 (per reference)
    const float* w1       = (const float*)d_in[6];
    const float* w2       = (const float*)d_in[7];
    const float* dw       = (const float*)d_in[8];
    const float* db       = (const float*)d_in[9];
    float* out = (float*)d_out;

    char* ws = (char*)d_ws;
    short* x1  = (short*)ws;                              // 67,108,864 B
    short* x2  = (short*)(ws + 67108864);                 // 67,108,864 B (also fx)
    short* wm  = (short*)(ws + 134217728);                // 9,437,184 B
    short* dwm = (short*)(ws + 143654912);                // 1,048,576 B
    float* dv  = (float*)(ws + 144703488);                // 16,384 B

    demod_kernel    <<<4096, 128, 0, stream>>>(w1, w2, sm1, ss1, dv);
    expand_kernel   <<<4608, 256, 0, stream>>>(w1, w2, sm1, ss1, dv, wm);
    dwexpand_kernel <<<2048, 256, 0, stream>>>(dw, dwm);
    nchw2nhwc_kernel<<<2048, 256, 0, stream>>>(features, x2);
    conv3x3_mfma    <<<2048, 256, 0, stream>>>(x2, wm, nullptr, x1);
    conv3x3_mfma    <<<2048, 256, 0, stream>>>(x1, wm + 16 * 147456, x1, x2);
    downconv_mfma   <<<1024, 256, 0, stream>>>(x2, dwm, db, out);
}

// Round 10
// 481.600 us; speedup vs baseline: 1.2565x; 1.0505x over previous
//
#include <hip/hip_runtime.h>
#include <hip/hip_bf16.h>

constexpr int B  = 16;
constexpr int C  = 128;
constexpr int H  = 128;
constexpr int W  = 128;
constexpr int CO = 256;
constexpr int HO = 64;
constexpr int WO = 64;

#define EPSV   1e-8f
#define SLOPE  0.2f

typedef short bf16x8 __attribute__((ext_vector_type(8)));
typedef float f32x4  __attribute__((ext_vector_type(4)));

__device__ __forceinline__ short f2bs(float v) {
    __hip_bfloat16 h = __float2bfloat16(v);
    return *(short*)&h;
}
__device__ __forceinline__ float bs2f(short s) {
    __hip_bfloat16 h = *(__hip_bfloat16*)&s;
    return __bfloat162float(h);
}

// ---------------------------------------------------------------------------
// demod: d[conv][b][o] = rsqrt(sum_{i,k}(w[o,i,k]*(s[b,i]+1))^2 + eps)
// ---------------------------------------------------------------------------
__global__ __launch_bounds__(128) void demod_kernel(
    const float* __restrict__ w1, const float* __restrict__ w2,
    const float* __restrict__ s1, const float* __restrict__ s2,
    float* __restrict__ d)
{
    int bid  = blockIdx.x;          // conv*2048 + b*128 + o
    int conv = bid >> 11;
    int b    = (bid >> 7) & 15;
    int o    = bid & 127;
    const float* w = conv ? w2 : w1;
    const float* s = conv ? s2 : s1;
    int i = threadIdx.x;
    float sv = s[b * C + i] + 1.0f;
    const float* wp = w + (o * C + i) * 9;
    float sum = 0.f;
    #pragma unroll
    for (int k = 0; k < 9; ++k) { float t = wp[k] * sv; sum += t * t; }
    #pragma unroll
    for (int off = 32; off; off >>= 1) sum += __shfl_down(sum, off);
    __shared__ float red[2];
    if ((threadIdx.x & 63) == 0) red[threadIdx.x >> 6] = sum;
    __syncthreads();
    if (threadIdx.x == 0) d[bid] = rsqrtf(red[0] + red[1] + EPSV);
}

// ---------------------------------------------------------------------------
// expand -> wave-coalesced B-fragment tiling (r8: 4 ic per thread,
// float4 style load + 8B packed store).
// wm[cb][tap][ocT=oc>>4][icC=ic>>5][(oc&15)*32 + (ic&31)]   (bf16)
// ---------------------------------------------------------------------------
__global__ __launch_bounds__(256) void expand_kernel(
    const float* __restrict__ w1, const float* __restrict__ w2,
    const float* __restrict__ s1, const float* __restrict__ s2,
    const float* __restrict__ d, short* __restrict__ wm)
{
    int idx = blockIdx.x * 256 + threadIdx.x;   // 288*128*32 = 1,179,648
    int icq = idx & 31;                          // ic quad index
    int oc  = (idx >> 5) & 127;
    int t   = idx >> 12;                         // cb*9+tap, < 288
    int tap = t % 9;
    int cb  = t / 9;                             // conv*16+b
    int b   = cb & 15;
    int conv= cb >> 4;
    const float* w = conv ? w2 : w1;
    const float* s = conv ? s2 : s1;
    int ic0 = icq * 4;

    float4 sv = *(const float4*)&s[b * C + ic0];
    float dv = d[(conv * B + b) * C + oc];
    const float* wp = w + (oc * C + ic0) * 9 + tap;

    short vs[4];
    vs[0] = f2bs(wp[ 0] * (sv.x + 1.0f) * dv);
    vs[1] = f2bs(wp[ 9] * (sv.y + 1.0f) * dv);
    vs[2] = f2bs(wp[18] * (sv.z + 1.0f) * dv);
    vs[3] = f2bs(wp[27] * (sv.w + 1.0f) * dv);

    int dst = cb * 147456
            + ((tap * 8 + (oc >> 4)) * 4 + (ic0 >> 5)) * 512
            + (oc & 15) * 32 + (ic0 & 31);
    *(uint2*)&wm[dst] = *(uint2*)vs;
}

// ---------------------------------------------------------------------------
// dwexpand: dwm[tap][ocT=oc>>4 (16)][icC=ic>>5 (4)][(oc&15)*32+(ic&31)]
// ---------------------------------------------------------------------------
__global__ __launch_bounds__(256) void dwexpand_kernel(
    const float* __restrict__ dw, short* __restrict__ dwm)
{
    int idx = blockIdx.x * 256 + threadIdx.x;   // 16*256*128 = 524288
    int ic  = idx & 127;
    int oc  = (idx >> 7) & 255;
    int tap = idx >> 15;
    int dst = ((tap * 16 + (oc >> 4)) * 4 + (ic >> 5)) * 512
            + (oc & 15) * 32 + (ic & 31);
    dwm[dst] = f2bs(dw[(oc * C + ic) * 16 + tap]);
}

// ---------------------------------------------------------------------------
// nchw(f32) -> nhwc(bf16) transpose of features.
// ---------------------------------------------------------------------------
__global__ __launch_bounds__(256) void nchw2nhwc_kernel(
    const float* __restrict__ in, short* __restrict__ out)
{
    __shared__ short s[128 * 136];
    int bid = blockIdx.x;                   // b*128 + h
    int h = bid & 127, b = bid >> 7;
    int tid = threadIdx.x;
    for (int i = tid; i < 128 * 32; i += 256) {
        int w4 = i & 31, ic = i >> 5;
        float4 v = *(const float4*)&in[((b * C + ic) * H + h) * W + w4 * 4];
        s[(w4 * 4 + 0) * 136 + ic] = f2bs(v.x);
        s[(w4 * 4 + 1) * 136 + ic] = f2bs(v.y);
        s[(w4 * 4 + 2) * 136 + ic] = f2bs(v.z);
        s[(w4 * 4 + 3) * 136 + ic] = f2bs(v.w);
    }
    __syncthreads();
    for (int i = tid; i < 128 * 16; i += 256) {
        int icg = i & 15, w = i >> 4;
        *(uint4*)&out[((b * H + h) * W + w) * C + icg * 8] =
            *(uint4*)&s[w * 136 + icg * 8];
    }
}

// ---------------------------------------------------------------------------
// conv3x3 MFMA implicit GEMM — r9 retile (best verified: ~111 us).
// wave = 128px x 32oc: per-wave global loads halved, weight frags dedup'd
// across waves (r9: -22%, MfmaUtil 29%). FROZEN this round.
// LESSONS: r5 ring-3 null; r7 per-step barriers regress; r9 retile WIN.
// ---------------------------------------------------------------------------
__global__ __launch_bounds__(256, 3) void conv3x3_mfma(
    const short* __restrict__ in, const short* __restrict__ wmc,
    const short* __restrict__ res, short* __restrict__ out)
{
    __shared__ short sIn[10 * 18 * 136];   // 48,960 B

    // T1: XCD-aware swizzle (r6: weights L2-resident per XCD; keep).
    int bid0 = blockIdx.x;
    int bid  = (bid0 & 7) * 256 + (bid0 >> 3);

    int wt = bid & 7, ht = (bid >> 3) & 15, b = bid >> 7;
    int w0 = wt * 16, h0 = ht * 8;
    int tid  = threadIdx.x;
    int lane = tid & 63, wv = tid >> 6;
    int q = lane >> 4, l15 = lane & 15;

    for (int i = tid; i < 10 * 18 * 16; i += 256) {
        int icg = i & 15;
        int t = i >> 4;
        int wl = t % 18, hl = t / 18;
        int gh = h0 - 1 + hl, gw = w0 - 1 + wl;
        uint4 v = make_uint4(0u, 0u, 0u, 0u);
        if ((unsigned)gh < (unsigned)H && (unsigned)gw < (unsigned)W)
            v = *(const uint4*)&in[((b * H + gh) * W + gw) * C + icg * 8];
        *(uint4*)&sIn[(hl * 18 + wl) * 136 + icg * 8] = v;
    }
    __syncthreads();

    const short* wb = wmc + b * 147456;

    f32x4 acc[8][2];
    #pragma unroll
    for (int mt = 0; mt < 8; ++mt)
        #pragma unroll
        for (int nt = 0; nt < 2; ++nt)
            acc[mt][nt] = (f32x4){0.f, 0.f, 0.f, 0.f};

    bf16x8 af[2][8];   // pixels (LDS), parity s&1, distance 1; 8 h-rows
    bf16x8 bf[2][2];   // weights (global), parity s&1, distance 1; 2 oc-tiles

    // K-step s = tap*4 + c  (tap = s>>2, c = s&3)
    auto ldAF = [&](int slot, int tap, int c) {
        int dh = tap / 3, dw = tap - dh * 3;
        #pragma unroll
        for (int mt = 0; mt < 8; ++mt)
            af[slot][mt] = *(const bf16x8*)&sIn[((mt + dh) * 18 + l15 + dw) * 136
                                                + c * 32 + q * 8];
    };
    auto ldBF = [&](int slot, int tap, int c) {
        #pragma unroll
        for (int nt = 0; nt < 2; ++nt)
            bf[slot][nt] = *(const bf16x8*)&wb[((tap * 8 + wv * 2 + nt) * 4 + c) * 512
                                               + l15 * 32 + q * 8];
    };

    // prologue: step 0 operands
    ldAF(0, 0, 0);
    ldBF(0, 0, 0);

    #pragma unroll
    for (int s = 0; s < 36; ++s) {
        // prefetch step s+1 (global first: longer latency)
        int s1 = (s + 1 < 36) ? s + 1 : s;       // dummy at tail
        ldBF((s + 1) & 1, s1 >> 2, s1 & 3);
        ldAF((s + 1) & 1, s1 >> 2, s1 & 3);
        // compute step s (T5)
        __builtin_amdgcn_s_setprio(1);
        #pragma unroll
        for (int mt = 0; mt < 8; ++mt)
            #pragma unroll
            for (int nt = 0; nt < 2; ++nt)
                acc[mt][nt] = __builtin_amdgcn_mfma_f32_16x16x32_bf16(
                    af[s & 1][mt], bf[s & 1][nt], acc[mt][nt], 0, 0, 0);
        __builtin_amdgcn_s_setprio(0);
    }

    bool has_res = (res != nullptr);
    #pragma unroll
    for (int mt = 0; mt < 8; ++mt) {
        int h = h0 + mt;
        #pragma unroll
        for (int nt = 0; nt < 2; ++nt) {
            int oc = wv * 32 + nt * 16 + l15;
            #pragma unroll
            for (int reg = 0; reg < 4; ++reg) {
                int w = w0 + q * 4 + reg;
                int idx = ((b * H + h) * W + w) * C + oc;
                float v = acc[mt][nt][reg];
                if (has_res) v += bs2f(res[idx]);
                v = v >= 0.f ? v : SLOPE * v;
                out[idx] = f2bs(v);
            }
        }
    }
}

// ---------------------------------------------------------------------------
// downconv MFMA — round-10 retile: wave = 128px x 32oc (transfer of r9's
// confirmed mechanism). OLD: waves split (wo=oc-half, wp=px-half) -> wp-pair
// waves loaded IDENTICAL af weight frags from global (2x duplicated VMEM,
// the exact defect r9 removed from conv3x3 for -22%). NEW: each wave owns
// ocT = ot*8 + wv*2 + {0,1} (2 frags/step, dedup'd) x all 8 oh-rows
// (bf 8 frags/step from LDS — cheap duplication).
// Register audit: acc[2][8]=64 + af[4][2]=32 (keep r2's distance-3 ring)
// + bf[2][8]=64 + misc~30 = 190 <= 256 (2 waves/SIMD, LDS-capped anyway).
// LESSONS: r1 spill (>arch budget), r3 restructure regress, r4 setprio WIN.
// TRIPWIRE: WRITE > 80MB = spill -> revert to r9 form.
// ---------------------------------------------------------------------------
__global__ __launch_bounds__(256, 2) void downconv_mfma(
    const short* __restrict__ in, const short* __restrict__ dwm,
    const float* __restrict__ db, float* __restrict__ out)
{
    __shared__ short sIn[19 * 2 * 18 * 40];   // 54,720 B

    int bid = blockIdx.x;
    int wt = bid & 3;  bid >>= 2;
    int ht = bid & 7;  bid >>= 3;
    int ot = bid & 1;  bid >>= 1;
    int b  = bid;
    int ow0 = wt * 16, oh0 = ht * 8, oc0 = ot * 128;

    int tid  = threadIdx.x;
    int lane = tid & 63, wv = tid >> 6;
    int q = lane >> 4, l15 = lane & 15;

    f32x4 acc[2][8];
    #pragma unroll
    for (int mt = 0; mt < 2; ++mt)
        #pragma unroll
        for (int nt = 0; nt < 8; ++nt)
            acc[mt][nt] = (f32x4){0.f, 0.f, 0.f, 0.f};

    int ocTb = ot * 8 + wv * 2;   // this wave's oc-tile base (16-oc units)

    // ---- direct stage of ic-chunk 0 ----
    for (int i = tid; i < 19 * 35 * 4; i += 256) {
        int icg = i & 3;
        int t = i >> 2;
        int wl = t % 35, hl = t / 35;
        int gh = 2 * oh0 - 1 + hl, gw = 2 * ow0 - 1 + wl;
        uint4 v = make_uint4(0u, 0u, 0u, 0u);
        if ((unsigned)gh < (unsigned)H && (unsigned)gw < (unsigned)W)
            v = *(const uint4*)&in[((b * H + gh) * W + gw) * C + icg * 8];
        *(uint4*)&sIn[((hl * 2 + (wl & 1)) * 18 + (wl >> 1)) * 40 + icg * 8] = v;
    }

    bf16x8 af[4][2];   // A ring: slot = (c*16+tap) & 3, filled 3 steps ahead
    bf16x8 bf[2][8];   // B parity: slot = tap & 1; 8 oh-rows

    // A-pipeline prologue: steps 0..2 (c=0, taps 0..2) — no LDS dependence
    #pragma unroll
    for (int s = 0; s < 3; ++s)
        #pragma unroll
        for (int mt = 0; mt < 2; ++mt)
            af[s][mt] = *(const bf16x8*)&dwm[((s * 16 + ocTb + mt) * 4 + 0) * 512
                                             + l15 * 32 + q * 8];

    __syncthreads();

    #pragma unroll 1
    for (int c = 0; c < 4; ++c) {
        // B prologue: tap 0 (dh=0, dw=0): input row hl = 2*j
        #pragma unroll
        for (int nt = 0; nt < 8; ++nt)
            bf[0][nt] = *(const bf16x8*)&sIn[((2 * nt) * 2 * 18 + l15) * 40 + q * 8];

        #pragma unroll
        for (int tap = 0; tap < 16; ++tap) {
            // A prefetch: flattened step s+3 (crosses the c boundary)
            {
                int sp = c * 16 + tap + 3;
                sp = sp < 63 ? sp : 63;          // dummy tail prefetch
                int pc = sp >> 4, pt = sp & 15;
                #pragma unroll
                for (int mt = 0; mt < 2; ++mt)
                    af[(tap + 3) & 3][mt] =
                        *(const bf16x8*)&dwm[((pt * 16 + ocTb + mt) * 4 + pc) * 512
                                             + l15 * 32 + q * 8];
            }
            // B prefetch: tap+1
            {
                int tapn = (tap + 1 < 16) ? tap + 1 : tap;
                int dhn = tapn >> 2, dwn = tapn & 3;
                #pragma unroll
                for (int nt = 0; nt < 8; ++nt) {
                    int hl = 2 * nt + dhn;
                    bf[(tap + 1) & 1][nt] =
                        *(const bf16x8*)&sIn[((hl * 2 + (dwn & 1)) * 18 + l15 + (dwn >> 1)) * 40
                                             + q * 8];
                }
            }
            // compute tap (T5)
            __builtin_amdgcn_s_setprio(1);
            #pragma unroll
            for (int mt = 0; mt < 2; ++mt)
                #pragma unroll
                for (int nt = 0; nt < 8; ++nt)
                    acc[mt][nt] = __builtin_amdgcn_mfma_f32_16x16x32_bf16(
                        af[tap & 3][mt], bf[tap & 1][nt], acc[mt][nt], 0, 0, 0);
            __builtin_amdgcn_s_setprio(0);
        }

        if (c < 3) {
            __syncthreads();                     // all reads of chunk c done
            for (int i = tid; i < 19 * 35 * 4; i += 256) {
                int icg = i & 3;
                int t = i >> 2;
                int wl = t % 35, hl = t / 35;
                int gh = 2 * oh0 - 1 + hl, gw = 2 * ow0 - 1 + wl;
                uint4 v = make_uint4(0u, 0u, 0u, 0u);
                if ((unsigned)gh < (unsigned)H && (unsigned)gw < (unsigned)W)
                    v = *(const uint4*)&in[((b * H + gh) * W + gw) * C
                                           + (c + 1) * 32 + icg * 8];
                *(uint4*)&sIn[((hl * 2 + (wl & 1)) * 18 + (wl >> 1)) * 40 + icg * 8] = v;
            }
            __syncthreads();                     // chunk c+1 visible
        }
    }

    #pragma unroll
    for (int mt = 0; mt < 2; ++mt) {
        #pragma unroll
        for (int reg = 0; reg < 4; ++reg) {
            int oc = oc0 + wv * 32 + mt * 16 + q * 4 + reg;
            float bias = db[oc];
            #pragma unroll
            for (int nt = 0; nt < 8; ++nt) {
                int oh = oh0 + nt;
                int ow = ow0 + l15;
                out[((b * CO + oc) * HO + oh) * WO + ow] = acc[mt][nt][reg] + bias;
            }
        }
    }
}

// ---------------------------------------------------------------------------
extern "C" void kernel_launch(void* const* d_in, const int* in_sizes, int n_in,
                              void* d_out, int out_size, void* d_ws, size_t ws_size,
                              hipStream_t stream) {
    const float* features = (const float*)d_in[0];
    const float* sm1      = (const float*)d_in[1];   // style_mean1 -> s1
    const float* ss1      = (const float*)d_in[2];   // style_std1  -> s2 (per reference)
    const float* w1       = (const float*)d_in[6];
    const float* w2       = (const float*)d_in[7];
    const float* dw       = (const float*)d_in[8];
    const float* db       = (const float*)d_in[9];
    float* out = (float*)d_out;

    char* ws = (char*)d_ws;
    short* x1  = (short*)ws;                              // 67,108,864 B
    short* x2  = (short*)(ws + 67108864);                 // 67,108,864 B (also fx)
    short* wm  = (short*)(ws + 134217728);                // 9,437,184 B
    short* dwm = (short*)(ws + 143654912);                // 1,048,576 B
    float* dv  = (float*)(ws + 144703488);                // 16,384 B

    demod_kernel    <<<4096, 128, 0, stream>>>(w1, w2, sm1, ss1, dv);
    expand_kernel   <<<4608, 256, 0, stream>>>(w1, w2, sm1, ss1, dv, wm);
    dwexpand_kernel <<<2048, 256, 0, stream>>>(dw, dwm);
    nchw2nhwc_kernel<<<2048, 256, 0, stream>>>(features, x2);
    conv3x3_mfma    <<<2048, 256, 0, stream>>>(x2, wm, nullptr, x1);
    conv3x3_mfma    <<<2048, 256, 0, stream>>>(x1, wm + 16 * 147456, x1, x2);
    downconv_mfma   <<<1024, 256, 0, stream>>>(x2, dwm, db, out);
}

// Round 11
// 473.481 us; speedup vs baseline: 1.2780x; 1.0171x over previous
//
#include <hip/hip_runtime.h>
#include <hip/hip_bf16.h>

constexpr int B  = 16;
constexpr int C  = 128;
constexpr int H  = 128;
constexpr int W  = 128;
constexpr int CO = 256;
constexpr int HO = 64;
constexpr int WO = 64;

#define EPSV   1e-8f
#define SLOPE  0.2f

typedef short bf16x8 __attribute__((ext_vector_type(8)));
typedef float f32x4  __attribute__((ext_vector_type(4)));

__device__ __forceinline__ short f2bs(float v) {
    __hip_bfloat16 h = __float2bfloat16(v);
    return *(short*)&h;
}
__device__ __forceinline__ float bs2f(short s) {
    __hip_bfloat16 h = *(__hip_bfloat16*)&s;
    return __bfloat162float(h);
}

// ---------------------------------------------------------------------------
// prep: fused nchw2nhwc (blocks 0-2047) + dwexpand (2048-4095)
//       + demod (4096-8191).  Independent parts, one launch (saves 2 gaps).
// ---------------------------------------------------------------------------
__global__ __launch_bounds__(256) void prep_kernel(
    const float* __restrict__ in, short* __restrict__ outNhwc,
    const float* __restrict__ dw, short* __restrict__ dwm,
    const float* __restrict__ w1, const float* __restrict__ w2,
    const float* __restrict__ s1, const float* __restrict__ s2,
    float* __restrict__ d)
{
    __shared__ short s[128 * 136];
    int gb  = blockIdx.x;
    int tid = threadIdx.x;

    if (gb < 2048) {
        // ---- nchw(f32) -> nhwc(bf16) transpose ----
        int h = gb & 127, b = gb >> 7;
        for (int i = tid; i < 128 * 32; i += 256) {
            int w4 = i & 31, ic = i >> 5;
            float4 v = *(const float4*)&in[((b * C + ic) * H + h) * W + w4 * 4];
            s[(w4 * 4 + 0) * 136 + ic] = f2bs(v.x);
            s[(w4 * 4 + 1) * 136 + ic] = f2bs(v.y);
            s[(w4 * 4 + 2) * 136 + ic] = f2bs(v.z);
            s[(w4 * 4 + 3) * 136 + ic] = f2bs(v.w);
        }
        __syncthreads();
        for (int i = tid; i < 128 * 16; i += 256) {
            int icg = i & 15, w = i >> 4;
            *(uint4*)&outNhwc[((b * H + h) * W + w) * C + icg * 8] =
                *(uint4*)&s[w * 136 + icg * 8];
        }
    } else if (gb < 4096) {
        // ---- dwexpand: dwm[tap][ocT][icC][(oc&15)*32+(ic&31)] ----
        int idx = (gb - 2048) * 256 + tid;
        int ic  = idx & 127;
        int oc  = (idx >> 7) & 255;
        int tap = idx >> 15;
        int dst = ((tap * 16 + (oc >> 4)) * 4 + (ic >> 5)) * 512
                + (oc & 15) * 32 + (ic & 31);
        dwm[dst] = f2bs(dw[(oc * C + ic) * 16 + tap]);
    } else {
        // ---- demod: d[conv][b][o] (tid<128 active; syncthreads unguarded) ----
        int bid  = gb - 4096;
        int conv = bid >> 11;
        int b    = (bid >> 7) & 15;
        int o    = bid & 127;
        const float* w = conv ? w2 : w1;
        const float* sv = conv ? s2 : s1;
        float sum = 0.f;
        if (tid < 128) {
            float svv = sv[b * C + tid] + 1.0f;
            const float* wp = w + (o * C + tid) * 9;
            #pragma unroll
            for (int k = 0; k < 9; ++k) { float t = wp[k] * svv; sum += t * t; }
        }
        #pragma unroll
        for (int off = 32; off; off >>= 1) sum += __shfl_down(sum, off);
        __shared__ float red[4];
        if ((tid & 63) == 0) red[tid >> 6] = sum;
        __syncthreads();
        if (tid == 0) d[bid] = rsqrtf(red[0] + red[1] + EPSV);
    }
}

// ---------------------------------------------------------------------------
// expand -> wave-coalesced B-fragment tiling (r8: 4 ic per thread,
// float4 style load + 8B packed store).
// wm[cb][tap][ocT=oc>>4][icC=ic>>5][(oc&15)*32 + (ic&31)]   (bf16)
// ---------------------------------------------------------------------------
__global__ __launch_bounds__(256) void expand_kernel(
    const float* __restrict__ w1, const float* __restrict__ w2,
    const float* __restrict__ s1, const float* __restrict__ s2,
    const float* __restrict__ d, short* __restrict__ wm)
{
    int idx = blockIdx.x * 256 + threadIdx.x;   // 288*128*32 = 1,179,648
    int icq = idx & 31;                          // ic quad index
    int oc  = (idx >> 5) & 127;
    int t   = idx >> 12;                         // cb*9+tap, < 288
    int tap = t % 9;
    int cb  = t / 9;                             // conv*16+b
    int b   = cb & 15;
    int conv= cb >> 4;
    const float* w = conv ? w2 : w1;
    const float* s = conv ? s2 : s1;
    int ic0 = icq * 4;

    float4 sv = *(const float4*)&s[b * C + ic0];
    float dv = d[(conv * B + b) * C + oc];
    const float* wp = w + (oc * C + ic0) * 9 + tap;

    short vs[4];
    vs[0] = f2bs(wp[ 0] * (sv.x + 1.0f) * dv);
    vs[1] = f2bs(wp[ 9] * (sv.y + 1.0f) * dv);
    vs[2] = f2bs(wp[18] * (sv.z + 1.0f) * dv);
    vs[3] = f2bs(wp[27] * (sv.w + 1.0f) * dv);

    int dst = cb * 147456
            + ((tap * 8 + (oc >> 4)) * 4 + (ic0 >> 5)) * 512
            + (oc & 15) * 32 + (ic0 & 31);
    *(uint2*)&wm[dst] = *(uint2*)vs;
}

// ---------------------------------------------------------------------------
// conv3x3 MFMA implicit GEMM — r9 retile (wave = 128px x 32oc; dedup'd
// weight loads: -22%, MfmaUtil 29%).  Round-11: SALU-ified addressing —
// wv pinned to SGPR via readfirstlane, lane-invariant offsets hoisted so
// af reads fold to ds_read offset:N and bf addresses are SGPR-base math.
// Evidence: VALUBusy 22% ~= 200 VALU-cy/wave-step vs 80 MFMA-cy — VALU is
// the longer pipe; divergent-address chains are the candidate.
// LESSONS: r5 ring-3 null; r7 per-step barriers regress; r9 retile WIN.
// ---------------------------------------------------------------------------
__global__ __launch_bounds__(256, 3) void conv3x3_mfma(
    const short* __restrict__ in, const short* __restrict__ wmc,
    const short* __restrict__ res, short* __restrict__ out)
{
    __shared__ short sIn[10 * 18 * 136];   // 48,960 B

    // T1: XCD-aware swizzle (r6: weights L2-resident per XCD; keep).
    int bid0 = blockIdx.x;
    int bid  = (bid0 & 7) * 256 + (bid0 >> 3);

    int wt = bid & 7, ht = (bid >> 3) & 15, b = bid >> 7;
    int w0 = wt * 16, h0 = ht * 8;
    int tid  = threadIdx.x;
    int lane = tid & 63;
    int wv   = __builtin_amdgcn_readfirstlane(tid >> 6);   // SGPR wave idx
    int q = lane >> 4, l15 = lane & 15;

    for (int i = tid; i < 10 * 18 * 16; i += 256) {
        int icg = i & 15;
        int t = i >> 4;
        int wl = t % 18, hl = t / 18;
        int gh = h0 - 1 + hl, gw = w0 - 1 + wl;
        uint4 v = make_uint4(0u, 0u, 0u, 0u);
        if ((unsigned)gh < (unsigned)H && (unsigned)gw < (unsigned)W)
            v = *(const uint4*)&in[((b * H + gh) * W + gw) * C + icg * 8];
        *(uint4*)&sIn[(hl * 18 + wl) * 136 + icg * 8] = v;
    }
    __syncthreads();

    // SGPR base for this wave's weight frags; VGPR lane offset hoisted once.
    const short* wbW = wmc + b * 147456 + wv * 4096;   // (wv*2 frags)*4c*512
    int bfLane = l15 * 32 + q * 8;                      // invariant VGPR
    const short* afB = sIn + l15 * 136 + q * 8;         // invariant LDS base

    f32x4 acc[8][2];
    #pragma unroll
    for (int mt = 0; mt < 8; ++mt)
        #pragma unroll
        for (int nt = 0; nt < 2; ++nt)
            acc[mt][nt] = (f32x4){0.f, 0.f, 0.f, 0.f};

    bf16x8 af[2][8];   // pixels (LDS), parity s&1, distance 1; 8 h-rows
    bf16x8 bf[2][2];   // weights (global), parity s&1, distance 1; 2 oc-tiles

    // K-step s = tap*4 + c  (tap = s>>2, c = s&3)
    auto ldAF = [&](int slot, int tap, int c) {
        int dh = tap / 3, dw = tap - dh * 3;
        #pragma unroll
        for (int mt = 0; mt < 8; ++mt)
            af[slot][mt] = *(const bf16x8*)(afB + (dh * 18 + dw) * 136 + c * 32
                                            + mt * 2448);
    };
    auto ldBF = [&](int slot, int tap, int c) {
        #pragma unroll
        for (int nt = 0; nt < 2; ++nt)
            bf[slot][nt] = *(const bf16x8*)(wbW + ((tap * 8 + nt) * 4 + c) * 512
                                            + bfLane);
    };

    // prologue: step 0 operands
    ldAF(0, 0, 0);
    ldBF(0, 0, 0);

    #pragma unroll
    for (int s = 0; s < 36; ++s) {
        // prefetch step s+1 (global first: longer latency)
        int s1 = (s + 1 < 36) ? s + 1 : s;       // dummy at tail
        ldBF((s + 1) & 1, s1 >> 2, s1 & 3);
        ldAF((s + 1) & 1, s1 >> 2, s1 & 3);
        // compute step s (T5)
        __builtin_amdgcn_s_setprio(1);
        #pragma unroll
        for (int mt = 0; mt < 8; ++mt)
            #pragma unroll
            for (int nt = 0; nt < 2; ++nt)
                acc[mt][nt] = __builtin_amdgcn_mfma_f32_16x16x32_bf16(
                    af[s & 1][mt], bf[s & 1][nt], acc[mt][nt], 0, 0, 0);
        __builtin_amdgcn_s_setprio(0);
    }

    bool has_res = (res != nullptr);
    #pragma unroll
    for (int mt = 0; mt < 8; ++mt) {
        int h = h0 + mt;
        #pragma unroll
        for (int nt = 0; nt < 2; ++nt) {
            int oc = wv * 32 + nt * 16 + l15;
            #pragma unroll
            for (int reg = 0; reg < 4; ++reg) {
                int w = w0 + q * 4 + reg;
                int idx = ((b * H + h) * W + w) * C + oc;
                float v = acc[mt][nt][reg];
                if (has_res) v += bs2f(res[idx]);
                v = v >= 0.f ? v : SLOPE * v;
                out[idx] = f2bs(v);
            }
        }
    }
}

// ---------------------------------------------------------------------------
// downconv MFMA — r10 retile (wave = 128px x 32oc, dedup'd weight loads)
// + r11 SALU addressing (readfirstlane wave idx, hoisted lane offsets).
// LESSONS: r1 spill, r3 restructure regress, r4 setprio WIN, r10 retile WIN.
// TRIPWIRE: WRITE > 80MB = spill -> revert.
// ---------------------------------------------------------------------------
__global__ __launch_bounds__(256, 2) void downconv_mfma(
    const short* __restrict__ in, const short* __restrict__ dwm,
    const float* __restrict__ db, float* __restrict__ out)
{
    __shared__ short sIn[19 * 2 * 18 * 40];   // 54,720 B

    int bid = blockIdx.x;
    int wt = bid & 3;  bid >>= 2;
    int ht = bid & 7;  bid >>= 3;
    int ot = bid & 1;  bid >>= 1;
    int b  = bid;
    int ow0 = wt * 16, oh0 = ht * 8, oc0 = ot * 128;

    int tid  = threadIdx.x;
    int lane = tid & 63;
    int wv   = __builtin_amdgcn_readfirstlane(tid >> 6);   // SGPR wave idx
    int q = lane >> 4, l15 = lane & 15;

    f32x4 acc[2][8];
    #pragma unroll
    for (int mt = 0; mt < 2; ++mt)
        #pragma unroll
        for (int nt = 0; nt < 8; ++nt)
            acc[mt][nt] = (f32x4){0.f, 0.f, 0.f, 0.f};

    int ocTb = ot * 8 + wv * 2;   // this wave's oc-tile base (16-oc units)

    // ---- direct stage of ic-chunk 0 ----
    for (int i = tid; i < 19 * 35 * 4; i += 256) {
        int icg = i & 3;
        int t = i >> 2;
        int wl = t % 35, hl = t / 35;
        int gh = 2 * oh0 - 1 + hl, gw = 2 * ow0 - 1 + wl;
        uint4 v = make_uint4(0u, 0u, 0u, 0u);
        if ((unsigned)gh < (unsigned)H && (unsigned)gw < (unsigned)W)
            v = *(const uint4*)&in[((b * H + gh) * W + gw) * C + icg * 8];
        *(uint4*)&sIn[((hl * 2 + (wl & 1)) * 18 + (wl >> 1)) * 40 + icg * 8] = v;
    }

    // SGPR weight base + invariant lane offsets.
    const short* dwW = dwm + ocTb * 2048;     // ocTb*4c*512
    int dwLane = l15 * 32 + q * 8;
    const short* bfB = sIn + l15 * 40 + q * 8;

    bf16x8 af[4][2];   // A ring: slot = (c*16+tap) & 3, filled 3 steps ahead
    bf16x8 bf[2][8];   // B parity: slot = tap & 1; 8 oh-rows

    // A-pipeline prologue: steps 0..2 (c=0, taps 0..2) — no LDS dependence
    #pragma unroll
    for (int s = 0; s < 3; ++s)
        #pragma unroll
        for (int mt = 0; mt < 2; ++mt)
            af[s][mt] = *(const bf16x8*)(dwW + (s * 16 + mt) * 2048 + dwLane);

    __syncthreads();

    #pragma unroll 1
    for (int c = 0; c < 4; ++c) {
        // B prologue: tap 0 (dh=0, dw=0): input row hl = 2*j
        #pragma unroll
        for (int nt = 0; nt < 8; ++nt)
            bf[0][nt] = *(const bf16x8*)(bfB + (2 * nt) * 2 * 18 * 40);

        #pragma unroll
        for (int tap = 0; tap < 16; ++tap) {
            // A prefetch: flattened step s+3 (crosses the c boundary)
            {
                int sp = c * 16 + tap + 3;
                sp = sp < 63 ? sp : 63;          // dummy tail prefetch
                int pc = sp >> 4, pt = sp & 15;
                #pragma unroll
                for (int mt = 0; mt < 2; ++mt)
                    af[(tap + 3) & 3][mt] =
                        *(const bf16x8*)(dwW + (pt * 16 + mt) * 2048 + pc * 512
                                         + dwLane);
            }
            // B prefetch: tap+1
            {
                int tapn = (tap + 1 < 16) ? tap + 1 : tap;
                int dhn = tapn >> 2, dwn = tapn & 3;
                #pragma unroll
                for (int nt = 0; nt < 8; ++nt) {
                    int hl = 2 * nt + dhn;
                    bf[(tap + 1) & 1][nt] =
                        *(const bf16x8*)(bfB + ((hl * 2 + (dwn & 1)) * 18
                                                + (dwn >> 1)) * 40);
                }
            }
            // compute tap (T5)
            __builtin_amdgcn_s_setprio(1);
            #pragma unroll
            for (int mt = 0; mt < 2; ++mt)
                #pragma unroll
                for (int nt = 0; nt < 8; ++nt)
                    acc[mt][nt] = __builtin_amdgcn_mfma_f32_16x16x32_bf16(
                        af[tap & 3][mt], bf[tap & 1][nt], acc[mt][nt], 0, 0, 0);
            __builtin_amdgcn_s_setprio(0);
        }

        if (c < 3) {
            __syncthreads();                     // all reads of chunk c done
            for (int i = tid; i < 19 * 35 * 4; i += 256) {
                int icg = i & 3;
                int t = i >> 2;
                int wl = t % 35, hl = t / 35;
                int gh = 2 * oh0 - 1 + hl, gw = 2 * ow0 - 1 + wl;
                uint4 v = make_uint4(0u, 0u, 0u, 0u);
                if ((unsigned)gh < (unsigned)H && (unsigned)gw < (unsigned)W)
                    v = *(const uint4*)&in[((b * H + gh) * W + gw) * C
                                           + (c + 1) * 32 + icg * 8];
                *(uint4*)&sIn[((hl * 2 + (wl & 1)) * 18 + (wl >> 1)) * 40 + icg * 8] = v;
            }
            __syncthreads();                     // chunk c+1 visible
        }
    }

    #pragma unroll
    for (int mt = 0; mt < 2; ++mt) {
        #pragma unroll
        for (int reg = 0; reg < 4; ++reg) {
            int oc = oc0 + wv * 32 + mt * 16 + q * 4 + reg;
            float bias = db[oc];
            #pragma unroll
            for (int nt = 0; nt < 8; ++nt) {
                int oh = oh0 + nt;
                int ow = ow0 + l15;
                out[((b * CO + oc) * HO + oh) * WO + ow] = acc[mt][nt][reg] + bias;
            }
        }
    }
}

// ---------------------------------------------------------------------------
extern "C" void kernel_launch(void* const* d_in, const int* in_sizes, int n_in,
                              void* d_out, int out_size, void* d_ws, size_t ws_size,
                              hipStream_t stream) {
    const float* features = (const float*)d_in[0];
    const float* sm1      = (const float*)d_in[1];   // style_mean1 -> s1
    const float* ss1      = (const float*)d_in[2];   // style_std1  -> s2 (per reference)
    const float* w1       = (const float*)d_in[6];
    const float* w2       = (const float*)d_in[7];
    const float* dw       = (const float*)d_in[8];
    const float* db       = (const float*)d_in[9];
    float* out = (float*)d_out;

    char* ws = (char*)d_ws;
    short* x1  = (short*)ws;                              // 67,108,864 B
    short* x2  = (short*)(ws + 67108864);                 // 67,108,864 B (also fx)
    short* wm  = (short*)(ws + 134217728);                // 9,437,184 B
    short* dwm = (short*)(ws + 143654912);                // 1,048,576 B
    float* dv  = (float*)(ws + 144703488);                // 16,384 B

    // prep: nchw2nhwc (0-2047) + dwexpand (2048-4095) + demod (4096-8191)
    prep_kernel   <<<8192, 256, 0, stream>>>(features, x2, dw, dwm,
                                             w1, w2, sm1, ss1, dv);
    expand_kernel <<<4608, 256, 0, stream>>>(w1, w2, sm1, ss1, dv, wm);
    conv3x3_mfma  <<<2048, 256, 0, stream>>>(x2, wm, nullptr, x1);
    conv3x3_mfma  <<<2048, 256, 0, stream>>>(x1, wm + 16 * 147456, x1, x2);
    downconv_mfma <<<1024, 256, 0, stream>>>(x2, dwm, db, out);
}

// Round 12
// 463.632 us; speedup vs baseline: 1.3052x; 1.0212x over previous
//
#include <hip/hip_runtime.h>
#include <hip/hip_bf16.h>

constexpr int B  = 16;
constexpr int C  = 128;
constexpr int H  = 128;
constexpr int W  = 128;
constexpr int CO = 256;
constexpr int HO = 64;
constexpr int WO = 64;

#define EPSV   1e-8f
#define SLOPE  0.2f

typedef short bf16x8 __attribute__((ext_vector_type(8)));
typedef float f32x4  __attribute__((ext_vector_type(4)));

__device__ __forceinline__ short f2bs(float v) {
    __hip_bfloat16 h = __float2bfloat16(v);
    return *(short*)&h;
}
__device__ __forceinline__ float bs2f(short s) {
    __hip_bfloat16 h = *(__hip_bfloat16*)&s;
    return __bfloat162float(h);
}

// ---------------------------------------------------------------------------
// prep: fused nchw2nhwc (blocks 0-2047) + dwexpand (2048-4095)
//       + demod (4096-8191).  Independent parts, one launch (saves 2 gaps).
// ---------------------------------------------------------------------------
__global__ __launch_bounds__(256) void prep_kernel(
    const float* __restrict__ in, short* __restrict__ outNhwc,
    const float* __restrict__ dw, short* __restrict__ dwm,
    const float* __restrict__ w1, const float* __restrict__ w2,
    const float* __restrict__ s1, const float* __restrict__ s2,
    float* __restrict__ d)
{
    __shared__ short s[128 * 136];
    int gb  = blockIdx.x;
    int tid = threadIdx.x;

    if (gb < 2048) {
        // ---- nchw(f32) -> nhwc(bf16) transpose ----
        int h = gb & 127, b = gb >> 7;
        for (int i = tid; i < 128 * 32; i += 256) {
            int w4 = i & 31, ic = i >> 5;
            float4 v = *(const float4*)&in[((b * C + ic) * H + h) * W + w4 * 4];
            s[(w4 * 4 + 0) * 136 + ic] = f2bs(v.x);
            s[(w4 * 4 + 1) * 136 + ic] = f2bs(v.y);
            s[(w4 * 4 + 2) * 136 + ic] = f2bs(v.z);
            s[(w4 * 4 + 3) * 136 + ic] = f2bs(v.w);
        }
        __syncthreads();
        for (int i = tid; i < 128 * 16; i += 256) {
            int icg = i & 15, w = i >> 4;
            *(uint4*)&outNhwc[((b * H + h) * W + w) * C + icg * 8] =
                *(uint4*)&s[w * 136 + icg * 8];
        }
    } else if (gb < 4096) {
        // ---- dwexpand: dwm[tap][ocT][icC][(oc&15)*32+(ic&31)] ----
        int idx = (gb - 2048) * 256 + tid;
        int ic  = idx & 127;
        int oc  = (idx >> 7) & 255;
        int tap = idx >> 15;
        int dst = ((tap * 16 + (oc >> 4)) * 4 + (ic >> 5)) * 512
                + (oc & 15) * 32 + (ic & 31);
        dwm[dst] = f2bs(dw[(oc * C + ic) * 16 + tap]);
    } else {
        // ---- demod: d[conv][b][o] (tid<128 active; syncthreads unguarded) ----
        int bid  = gb - 4096;
        int conv = bid >> 11;
        int b    = (bid >> 7) & 15;
        int o    = bid & 127;
        const float* w = conv ? w2 : w1;
        const float* sv = conv ? s2 : s1;
        float sum = 0.f;
        if (tid < 128) {
            float svv = sv[b * C + tid] + 1.0f;
            const float* wp = w + (o * C + tid) * 9;
            #pragma unroll
            for (int k = 0; k < 9; ++k) { float t = wp[k] * svv; sum += t * t; }
        }
        #pragma unroll
        for (int off = 32; off; off >>= 1) sum += __shfl_down(sum, off);
        __shared__ float red[4];
        if ((tid & 63) == 0) red[tid >> 6] = sum;
        __syncthreads();
        if (tid == 0) d[bid] = rsqrtf(red[0] + red[1] + EPSV);
    }
}

// ---------------------------------------------------------------------------
// expand -> wave-coalesced B-fragment tiling (r8: 4 ic per thread,
// float4 style load + 8B packed store).
// wm[cb][tap][ocT=oc>>4][icC=ic>>5][(oc&15)*32 + (ic&31)]   (bf16)
// ---------------------------------------------------------------------------
__global__ __launch_bounds__(256) void expand_kernel(
    const float* __restrict__ w1, const float* __restrict__ w2,
    const float* __restrict__ s1, const float* __restrict__ s2,
    const float* __restrict__ d, short* __restrict__ wm)
{
    int idx = blockIdx.x * 256 + threadIdx.x;   // 288*128*32 = 1,179,648
    int icq = idx & 31;                          // ic quad index
    int oc  = (idx >> 5) & 127;
    int t   = idx >> 12;                         // cb*9+tap, < 288
    int tap = t % 9;
    int cb  = t / 9;                             // conv*16+b
    int b   = cb & 15;
    int conv= cb >> 4;
    const float* w = conv ? w2 : w1;
    const float* s = conv ? s2 : s1;
    int ic0 = icq * 4;

    float4 sv = *(const float4*)&s[b * C + ic0];
    float dv = d[(conv * B + b) * C + oc];
    const float* wp = w + (oc * C + ic0) * 9 + tap;

    short vs[4];
    vs[0] = f2bs(wp[ 0] * (sv.x + 1.0f) * dv);
    vs[1] = f2bs(wp[ 9] * (sv.y + 1.0f) * dv);
    vs[2] = f2bs(wp[18] * (sv.z + 1.0f) * dv);
    vs[3] = f2bs(wp[27] * (sv.w + 1.0f) * dv);

    int dst = cb * 147456
            + ((tap * 8 + (oc >> 4)) * 4 + (ic0 >> 5)) * 512
            + (oc & 15) * 32 + (ic0 & 31);
    *(uint2*)&wm[dst] = *(uint2*)vs;
}

// ---------------------------------------------------------------------------
// conv3x3 MFMA implicit GEMM — r9 retile + r11 SALU addressing.
// Round-12: bf ring-3 (prefetch distance 2). REGIME CHANGE justification:
// r5's ring-3 null was at ~800cy/step (step > L2 latency, dist-1 covered).
// After r9/r11 the step is ~260cy < L2 latency (~300-500cy) -> dist-1
// exposes 100-300cy per step; dist-2 covers ~520cy. Cost +8 VGPR
// (152/wave <= 170 cap for 3 waves/SIMD).
// LESSONS: r7 per-step barriers regress; r9 retile WIN (-22%); r11 SALU ~+4%.
// NULL READING: flat 104-108 -> bf latency hidden by interleave; K-loop done.
// ---------------------------------------------------------------------------
__global__ __launch_bounds__(256, 3) void conv3x3_mfma(
    const short* __restrict__ in, const short* __restrict__ wmc,
    const short* __restrict__ res, short* __restrict__ out)
{
    __shared__ short sIn[10 * 18 * 136];   // 48,960 B

    // T1: XCD-aware swizzle (r6: weights L2-resident per XCD; keep).
    int bid0 = blockIdx.x;
    int bid  = (bid0 & 7) * 256 + (bid0 >> 3);

    int wt = bid & 7, ht = (bid >> 3) & 15, b = bid >> 7;
    int w0 = wt * 16, h0 = ht * 8;
    int tid  = threadIdx.x;
    int lane = tid & 63;
    int wv   = __builtin_amdgcn_readfirstlane(tid >> 6);   // SGPR wave idx
    int q = lane >> 4, l15 = lane & 15;

    for (int i = tid; i < 10 * 18 * 16; i += 256) {
        int icg = i & 15;
        int t = i >> 4;
        int wl = t % 18, hl = t / 18;
        int gh = h0 - 1 + hl, gw = w0 - 1 + wl;
        uint4 v = make_uint4(0u, 0u, 0u, 0u);
        if ((unsigned)gh < (unsigned)H && (unsigned)gw < (unsigned)W)
            v = *(const uint4*)&in[((b * H + gh) * W + gw) * C + icg * 8];
        *(uint4*)&sIn[(hl * 18 + wl) * 136 + icg * 8] = v;
    }
    __syncthreads();

    // SGPR base for this wave's weight frags; VGPR lane offset hoisted once.
    const short* wbW = wmc + b * 147456 + wv * 4096;   // (wv*2 frags)*4c*512
    int bfLane = l15 * 32 + q * 8;                      // invariant VGPR
    const short* afB = sIn + l15 * 136 + q * 8;         // invariant LDS base

    f32x4 acc[8][2];
    #pragma unroll
    for (int mt = 0; mt < 8; ++mt)
        #pragma unroll
        for (int nt = 0; nt < 2; ++nt)
            acc[mt][nt] = (f32x4){0.f, 0.f, 0.f, 0.f};

    bf16x8 af[2][8];   // pixels (LDS), parity s&1, distance 1; 8 h-rows
    bf16x8 bf[3][2];   // weights (global), ring s%3, DISTANCE 2; 2 oc-tiles

    // K-step s = tap*4 + c  (tap = s>>2, c = s&3)
    auto ldAF = [&](int slot, int tap, int c) {
        int dh = tap / 3, dw = tap - dh * 3;
        #pragma unroll
        for (int mt = 0; mt < 8; ++mt)
            af[slot][mt] = *(const bf16x8*)(afB + (dh * 18 + dw) * 136 + c * 32
                                            + mt * 2448);
    };
    auto ldBF = [&](int slot, int tap, int c) {
        #pragma unroll
        for (int nt = 0; nt < 2; ++nt)
            bf[slot][nt] = *(const bf16x8*)(wbW + ((tap * 8 + nt) * 4 + c) * 512
                                            + bfLane);
    };

    // prologue: af step 0; bf steps 0,1 (ring slots 0,1)
    ldAF(0, 0, 0);
    ldBF(0, 0, 0);
    ldBF(1, 0, 1);

    #pragma unroll
    for (int s = 0; s < 36; ++s) {
        // issue global prefetch first (longest latency): step s+2 into ring
        int s2 = (s + 2 < 36) ? s + 2 : s;       // dummy at tail
        ldBF((s + 2) % 3, s2 >> 2, s2 & 3);
        // LDS prefetch: step s+1
        int s1 = (s + 1 < 36) ? s + 1 : s;       // dummy at tail
        ldAF((s + 1) & 1, s1 >> 2, s1 & 3);
        // compute step s (T5)
        __builtin_amdgcn_s_setprio(1);
        #pragma unroll
        for (int mt = 0; mt < 8; ++mt)
            #pragma unroll
            for (int nt = 0; nt < 2; ++nt)
                acc[mt][nt] = __builtin_amdgcn_mfma_f32_16x16x32_bf16(
                    af[s & 1][mt], bf[s % 3][nt], acc[mt][nt], 0, 0, 0);
        __builtin_amdgcn_s_setprio(0);
    }

    bool has_res = (res != nullptr);
    #pragma unroll
    for (int mt = 0; mt < 8; ++mt) {
        int h = h0 + mt;
        #pragma unroll
        for (int nt = 0; nt < 2; ++nt) {
            int oc = wv * 32 + nt * 16 + l15;
            #pragma unroll
            for (int reg = 0; reg < 4; ++reg) {
                int w = w0 + q * 4 + reg;
                int idx = ((b * H + h) * W + w) * C + oc;
                float v = acc[mt][nt][reg];
                if (has_res) v += bs2f(res[idx]);
                v = v >= 0.f ? v : SLOPE * v;
                out[idx] = f2bs(v);
            }
        }
    }
}

// ---------------------------------------------------------------------------
// downconv MFMA — r10 retile + r11 SALU addressing. FROZEN this round.
// (af already distance-3 from global — the mechanism r12 adds to conv3x3.)
// LESSONS: r1 spill, r3 restructure regress, r4 setprio WIN, r10 retile WIN.
// ---------------------------------------------------------------------------
__global__ __launch_bounds__(256, 2) void downconv_mfma(
    const short* __restrict__ in, const short* __restrict__ dwm,
    const float* __restrict__ db, float* __restrict__ out)
{
    __shared__ short sIn[19 * 2 * 18 * 40];   // 54,720 B

    int bid = blockIdx.x;
    int wt = bid & 3;  bid >>= 2;
    int ht = bid & 7;  bid >>= 3;
    int ot = bid & 1;  bid >>= 1;
    int b  = bid;
    int ow0 = wt * 16, oh0 = ht * 8, oc0 = ot * 128;

    int tid  = threadIdx.x;
    int lane = tid & 63;
    int wv   = __builtin_amdgcn_readfirstlane(tid >> 6);   // SGPR wave idx
    int q = lane >> 4, l15 = lane & 15;

    f32x4 acc[2][8];
    #pragma unroll
    for (int mt = 0; mt < 2; ++mt)
        #pragma unroll
        for (int nt = 0; nt < 8; ++nt)
            acc[mt][nt] = (f32x4){0.f, 0.f, 0.f, 0.f};

    int ocTb = ot * 8 + wv * 2;   // this wave's oc-tile base (16-oc units)

    // ---- direct stage of ic-chunk 0 ----
    for (int i = tid; i < 19 * 35 * 4; i += 256) {
        int icg = i & 3;
        int t = i >> 2;
        int wl = t % 35, hl = t / 35;
        int gh = 2 * oh0 - 1 + hl, gw = 2 * ow0 - 1 + wl;
        uint4 v = make_uint4(0u, 0u, 0u, 0u);
        if ((unsigned)gh < (unsigned)H && (unsigned)gw < (unsigned)W)
            v = *(const uint4*)&in[((b * H + gh) * W + gw) * C + icg * 8];
        *(uint4*)&sIn[((hl * 2 + (wl & 1)) * 18 + (wl >> 1)) * 40 + icg * 8] = v;
    }

    // SGPR weight base + invariant lane offsets.
    const short* dwW = dwm + ocTb * 2048;     // ocTb*4c*512
    int dwLane = l15 * 32 + q * 8;
    const short* bfB = sIn + l15 * 40 + q * 8;

    bf16x8 af[4][2];   // A ring: slot = (c*16+tap) & 3, filled 3 steps ahead
    bf16x8 bf[2][8];   // B parity: slot = tap & 1; 8 oh-rows

    // A-pipeline prologue: steps 0..2 (c=0, taps 0..2) — no LDS dependence
    #pragma unroll
    for (int s = 0; s < 3; ++s)
        #pragma unroll
        for (int mt = 0; mt < 2; ++mt)
            af[s][mt] = *(const bf16x8*)(dwW + (s * 16 + mt) * 2048 + dwLane);

    __syncthreads();

    #pragma unroll 1
    for (int c = 0; c < 4; ++c) {
        // B prologue: tap 0 (dh=0, dw=0): input row hl = 2*j
        #pragma unroll
        for (int nt = 0; nt < 8; ++nt)
            bf[0][nt] = *(const bf16x8*)(bfB + (2 * nt) * 2 * 18 * 40);

        #pragma unroll
        for (int tap = 0; tap < 16; ++tap) {
            // A prefetch: flattened step s+3 (crosses the c boundary)
            {
                int sp = c * 16 + tap + 3;
                sp = sp < 63 ? sp : 63;          // dummy tail prefetch
                int pc = sp >> 4, pt = sp & 15;
                #pragma unroll
                for (int mt = 0; mt < 2; ++mt)
                    af[(tap + 3) & 3][mt] =
                        *(const bf16x8*)(dwW + (pt * 16 + mt) * 2048 + pc * 512
                                         + dwLane);
            }
            // B prefetch: tap+1
            {
                int tapn = (tap + 1 < 16) ? tap + 1 : tap;
                int dhn = tapn >> 2, dwn = tapn & 3;
                #pragma unroll
                for (int nt = 0; nt < 8; ++nt) {
                    int hl = 2 * nt + dhn;
                    bf[(tap + 1) & 1][nt] =
                        *(const bf16x8*)(bfB + ((hl * 2 + (dwn & 1)) * 18
                                                + (dwn >> 1)) * 40);
                }
            }
            // compute tap (T5)
            __builtin_amdgcn_s_setprio(1);
            #pragma unroll
            for (int mt = 0; mt < 2; ++mt)
                #pragma unroll
                for (int nt = 0; nt < 8; ++nt)
                    acc[mt][nt] = __builtin_amdgcn_mfma_f32_16x16x32_bf16(
                        af[tap & 3][mt], bf[tap & 1][nt], acc[mt][nt], 0, 0, 0);
            __builtin_amdgcn_s_setprio(0);
        }

        if (c < 3) {
            __syncthreads();                     // all reads of chunk c done
            for (int i = tid; i < 19 * 35 * 4; i += 256) {
                int icg = i & 3;
                int t = i >> 2;
                int wl = t % 35, hl = t / 35;
                int gh = 2 * oh0 - 1 + hl, gw = 2 * ow0 - 1 + wl;
                uint4 v = make_uint4(0u, 0u, 0u, 0u);
                if ((unsigned)gh < (unsigned)H && (unsigned)gw < (unsigned)W)
                    v = *(const uint4*)&in[((b * H + gh) * W + gw) * C
                                           + (c + 1) * 32 + icg * 8];
                *(uint4*)&sIn[((hl * 2 + (wl & 1)) * 18 + (wl >> 1)) * 40 + icg * 8] = v;
            }
            __syncthreads();                     // chunk c+1 visible
        }
    }

    #pragma unroll
    for (int mt = 0; mt < 2; ++mt) {
        #pragma unroll
        for (int reg = 0; reg < 4; ++reg) {
            int oc = oc0 + wv * 32 + mt * 16 + q * 4 + reg;
            float bias = db[oc];
            #pragma unroll
            for (int nt = 0; nt < 8; ++nt) {
                int oh = oh0 + nt;
                int ow = ow0 + l15;
                out[((b * CO + oc) * HO + oh) * WO + ow] = acc[mt][nt][reg] + bias;
            }
        }
    }
}

// ---------------------------------------------------------------------------
extern "C" void kernel_launch(void* const* d_in, const int* in_sizes, int n_in,
                              void* d_out, int out_size, void* d_ws, size_t ws_size,
                              hipStream_t stream) {
    const float* features = (const float*)d_in[0];
    const float* sm1      = (const float*)d_in[1];   // style_mean1 -> s1
    const float* ss1      = (const float*)d_in[2];   // style_std1  -> s2 (per reference)
    const float* w1       = (const float*)d_in[6];
    const float* w2       = (const float*)d_in[7];
    const float* dw       = (const float*)d_in[8];
    const float* db       = (const float*)d_in[9];
    float* out = (float*)d_out;

    char* ws = (char*)d_ws;
    short* x1  = (short*)ws;                              // 67,108,864 B
    short* x2  = (short*)(ws + 67108864);                 // 67,108,864 B (also fx)
    short* wm  = (short*)(ws + 134217728);                // 9,437,184 B
    short* dwm = (short*)(ws + 143654912);                // 1,048,576 B
    float* dv  = (float*)(ws + 144703488);                // 16,384 B

    // prep: nchw2nhwc (0-2047) + dwexpand (2048-4095) + demod (4096-8191)
    prep_kernel   <<<8192, 256, 0, stream>>>(features, x2, dw, dwm,
                                             w1, w2, sm1, ss1, dv);
    expand_kernel <<<4608, 256, 0, stream>>>(w1, w2, sm1, ss1, dv, wm);
    conv3x3_mfma  <<<2048, 256, 0, stream>>>(x2, wm, nullptr, x1);
    conv3x3_mfma  <<<2048, 256, 0, stream>>>(x1, wm + 16 * 147456, x1, x2);
    downconv_mfma <<<1024, 256, 0, stream>>>(x2, dwm, db, out);
}